// Round 11
// baseline (582.000 us; speedup 1.0000x reference)
//
#include <hip/hip_runtime.h>
#include <math.h>

typedef __attribute__((ext_vector_type(8))) short sh8;
typedef __attribute__((ext_vector_type(4))) short sh4;
typedef __attribute__((ext_vector_type(4))) float f4;
typedef __attribute__((ext_vector_type(4))) unsigned u4;

__device__ inline short f2bf(float f) {
    union { float f; unsigned u; } v; v.f = f;
    unsigned u = v.u;
    return (short)((u + 0x7fffu + ((u >> 16) & 1u)) >> 16);   // RNE
}
__device__ inline sh8 as_sh8(u4 v) { union { u4 u; sh8 s; } c; c.u = v; return c.s; }

// fast activations: native exp2/rcp, err ~1e-6
__device__ inline float sigm(float x)  { return __builtin_amdgcn_rcpf(1.f + __builtin_amdgcn_exp2f(-1.44269504f * x)); }
__device__ inline float tanha(float x) { return 1.f - 2.f * __builtin_amdgcn_rcpf(1.f + __builtin_amdgcn_exp2f(2.88539008f * x)); }

__device__ inline sh8 frag8(const float* __restrict__ p) {
    f4 a = *(const f4*)p;
    f4 b = *(const f4*)(p + 4);
    sh8 r;
    r[0]=f2bf(a[0]); r[1]=f2bf(a[1]); r[2]=f2bf(a[2]); r[3]=f2bf(a[3]);
    r[4]=f2bf(b[0]); r[5]=f2bf(b[1]); r[6]=f2bf(b[2]); r[7]=f2bf(b[3]);
    return r;
}

// Coherent 16B load: bypasses L1/L2, reads device coherence point (IF$).
__device__ inline u4 cload_u4(const void* p) {
    u4 r;
    asm volatile("global_load_dwordx4 %0, %1, off sc0 sc1" : "=v"(r) : "v"(p));
    return r;
}

// Group barrier (per-block 64B flag slots, monotonic epochs) — R8 proven form.
__device__ inline void grp_signal(int* myflag, int epoch) {
    asm volatile("s_waitcnt vmcnt(0)" ::: "memory");   // h-stores at coherence point
    __builtin_amdgcn_sched_barrier(0);
    __syncthreads();
    if (threadIdx.x == 0)
        __hip_atomic_store(myflag, epoch, __ATOMIC_RELAXED, __HIP_MEMORY_SCOPE_AGENT);
}
__device__ inline void grp_wait(const int* fbase, int nb, int epoch) {
    if (threadIdx.x < 64) {
        int lane = threadIdx.x;
        bool need = lane < nb;
        const int* fp = fbase + lane * 16;
        while (true) {
            int v = need ? __hip_atomic_load(fp, __ATOMIC_RELAXED, __HIP_MEMORY_SCOPE_AGENT)
                         : 0x7fffffff;
            if (__ballot(need && (v < epoch)) == 0ull) break;
            __builtin_amdgcn_s_sleep(1);
        }
    }
    __syncthreads();
}

// ---------------------------------------------------------------------------
__global__ void zero_ctr(int* c, int n) {
    int i = blockIdx.x * blockDim.x + threadIdx.x;
    if (i < n) c[i] = 0;
}

// ---------------------------------------------------------------------------
struct CvtPack { const float* s[7]; short* d[7]; int n4[7]; };
__global__ void cvt_bf16(CvtPack p) {
    int job = blockIdx.y;
    const f4* s = (const f4*)p.s[job];
    sh4* d = (sh4*)p.d[job];
    int n4 = p.n4[job];
    for (int i = blockIdx.x * blockDim.x + threadIdx.x; i < n4; i += gridDim.x * blockDim.x) {
        f4 v = s[i];
        sh4 o; o[0]=f2bf(v[0]); o[1]=f2bf(v[1]); o[2]=f2bf(v[2]); o[3]=f2bf(v[3]);
        d[i] = o;
    }
}

__global__ void bias_prep(const float* bihf, const float* bhhf,
                          const float* bihb, const float* bhhb, float* biasL) {
    int n = blockIdx.x * blockDim.x + threadIdx.x;
    biasL[n] = (n < 1024) ? bihf[n] + bhhf[n] : bihb[n - 1024] + bhhb[n - 1024];
}

// ---------------------------------------------------------------------------
__global__ void att_norm(const float* __restrict__ att, float* __restrict__ outA) {
    int row = blockIdx.x;
    int tid = threadIdx.x;
    const float* p = att + (size_t)row * 256;
    f4 v = *(const f4*)(p + tid * 4);
    float sum = v[0] + v[1] + v[2] + v[3];
    #pragma unroll
    for (int off = 32; off; off >>= 1) sum += __shfl_down(sum, off);
    float inv = 1.f / __shfl(sum, 0);
    f4 o; o[0]=v[0]*inv; o[1]=v[1]*inv; o[2]=v[2]*inv; o[3]=v[3]*inv;
    *(f4*)(outA + (size_t)row * 256 + tid * 4) = o;
}

// ---------------------------------------------------------------------------
__global__ __launch_bounds__(256)
void pool_gemm(const float* __restrict__ feature, const float* __restrict__ att,
               short* __restrict__ cseqb) {
    int bz = blockIdx.y;
    const float* A  = feature + (size_t)bz * 512 * 256;
    const float* Wt = att + (size_t)bz * 32 * 256;
    int wave = threadIdx.x >> 6, lane = threadIdx.x & 63, r = lane & 15, hh = lane >> 4;
    int m0 = blockIdx.x * 64 + wave * 16;
    f4 acc[2] = {};
    const float* ar = A  + (size_t)(m0 + r) * 256 + hh * 8;
    const float* w0 = Wt + (size_t)r * 256 + hh * 8;
    const float* w1 = Wt + (size_t)(16 + r) * 256 + hh * 8;
    for (int kk = 0; kk < 256; kk += 32) {
        sh8 af = frag8(ar + kk);
        acc[0] = __builtin_amdgcn_mfma_f32_16x16x32_bf16(af, frag8(w0 + kk), acc[0], 0, 0, 0);
        acc[1] = __builtin_amdgcn_mfma_f32_16x16x32_bf16(af, frag8(w1 + kk), acc[1], 0, 0, 0);
    }
    #pragma unroll
    for (int j = 0; j < 2; j++) {
        int t = j * 16 + r;
        #pragma unroll
        for (int reg = 0; reg < 4; reg++) {
            int c = m0 + hh * 4 + reg;
            cseqb[(size_t)t * 65536 + (size_t)bz * 512 + c] = f2bf(acc[j][reg]);
        }
    }
}

// ---------------------------------------------------------------------------
// gemm128: C[M,N] = A[M,K] @ W[N,K]^T + bias. bf16 operands, fp32 out.
template<int MODE>
__global__ __launch_bounds__(256)
void gemm128(const short* __restrict__ A, const short* __restrict__ W,
             const float* __restrict__ bias1, const float* __restrict__ bias2,
             float* __restrict__ out, int M, int N, int K) {
    __shared__ short lds[2][2][4096];
    const int tid = threadIdx.x, wave = tid >> 6, lane = tid & 63;
    const int r = lane & 15, hh = lane >> 4;
    const int wm = wave >> 1, wn = wave & 1;
    const int m0 = blockIdx.x * 128, n0 = blockIdx.y * 128;

    const int c0 = tid, c1 = 256 + tid;
    const int r0 = c0 >> 2, r1 = c1 >> 2;
    const int s0 = ((c0 & 3) ^ ((r0 >> 1) & 3));
    const int s1 = ((c1 & 3) ^ ((r1 >> 1) & 3));
    const short* gA0 = A + (size_t)(m0 + r0) * K + s0 * 8;
    const short* gA1 = A + (size_t)(m0 + r1) * K + s1 * 8;
    int wr0 = n0 + r0; if (wr0 > N - 1) wr0 = N - 1;
    int wr1 = n0 + r1; if (wr1 > N - 1) wr1 = N - 1;
    const short* gW0 = W + (size_t)wr0 * K + s0 * 8;
    const short* gW1 = W + (size_t)wr1 * K + s1 * 8;
    const int lo0 = (wave * 64) * 8, lo1 = (256 + wave * 64) * 8;

    auto stage = [&](int buf, int kt) {
        int ko = kt * 32;
        __builtin_amdgcn_global_load_lds((const __attribute__((address_space(1))) void*)(gA0 + ko),
            (__attribute__((address_space(3))) void*)&lds[buf][0][lo0], 16, 0, 0);
        __builtin_amdgcn_global_load_lds((const __attribute__((address_space(1))) void*)(gA1 + ko),
            (__attribute__((address_space(3))) void*)&lds[buf][0][lo1], 16, 0, 0);
        __builtin_amdgcn_global_load_lds((const __attribute__((address_space(1))) void*)(gW0 + ko),
            (__attribute__((address_space(3))) void*)&lds[buf][1][lo0], 16, 0, 0);
        __builtin_amdgcn_global_load_lds((const __attribute__((address_space(1))) void*)(gW1 + ko),
            (__attribute__((address_space(3))) void*)&lds[buf][1][lo1], 16, 0, 0);
    };

    f4 acc[4][4] = {};
    const int NT = K / 32;
    int cur = 0;

    stage(0, 0);
    __syncthreads();
    for (int kt = 0; kt < NT; ++kt) {
        if (kt + 1 < NT) stage(cur ^ 1, kt + 1);
        const char* As = (const char*)&lds[cur][0][0];
        const char* Ws = (const char*)&lds[cur][1][0];
        sh8 a[4], b[4];
        #pragma unroll
        for (int i = 0; i < 4; i++) {
            int row = wm * 64 + i * 16 + r;
            a[i] = *(const sh8*)(As + row * 64 + ((hh ^ ((row >> 1) & 3)) * 16));
        }
        #pragma unroll
        for (int i = 0; i < 4; i++) {
            int row = wn * 64 + i * 16 + r;
            b[i] = *(const sh8*)(Ws + row * 64 + ((hh ^ ((row >> 1) & 3)) * 16));
        }
        #pragma unroll
        for (int i = 0; i < 4; i++)
            #pragma unroll
            for (int j = 0; j < 4; j++)
                acc[i][j] = __builtin_amdgcn_mfma_f32_16x16x32_bf16(a[i], b[j], acc[i][j], 0, 0, 0);
        __syncthreads();
        cur ^= 1;
    }

    float bsj[4];
    #pragma unroll
    for (int j = 0; j < 4; j++) {
        int n = n0 + wn * 64 + j * 16 + r;
        int nc = n < N ? n : N - 1;
        bsj[j] = (bias1 ? bias1[nc] : 0.f) + (bias2 ? bias2[nc] : 0.f);
    }

    float* fl = (float*)&lds[0][0][0];
    #pragma unroll
    for (int hhalf = 0; hhalf < 2; hhalf++) {
        __syncthreads();
        if (wm == hhalf) {
            #pragma unroll
            for (int i = 0; i < 4; i++)
                #pragma unroll
                for (int j = 0; j < 4; j++) {
                    int col = wn * 64 + j * 16 + r;
                    #pragma unroll
                    for (int reg = 0; reg < 4; reg++)
                        fl[(i * 16 + hh * 4 + reg) * 128 + col] = acc[i][j][reg] + bsj[j];
                }
        }
        __syncthreads();
        #pragma unroll
        for (int it = 0; it < 8; it++) {
            int c = it * 256 + tid;
            int row = c >> 5, cf4 = c & 31;
            int n = n0 + cf4 * 4;
            int mrow = m0 + hhalf * 64 + row;
            size_t orow = (MODE == 0) ? (size_t)mrow
                                      : ((size_t)(mrow & 127) * 32 + (mrow >> 7));
            if (n + 3 < N) {
                *(f4*)&out[orow * N + n] = *(const f4*)&fl[row * 128 + cf4 * 4];
            } else {
                #pragma unroll
                for (int d = 0; d < 4; d++)
                    if (n + d < N) out[orow * N + n + d] = fl[row * 128 + cf4 * 4 + d];
            }
        }
    }
}

// ---------------------------------------------------------------------------
__global__ void emb_fill(const int* __restrict__ text, const float* __restrict__ emb,
                         short* __restrict__ xcatb) {
    int n = blockIdx.x;
    int t = n >> 7, b = n & 127;
    int idx = (t == 0) ? 0 : text[b * 32 + (t - 1)];
    const f4* src = (const f4*)(emb + (size_t)idx * 512);
    sh4* dst = (sh4*)(xcatb + (size_t)n * 1024 + 512);
    for (int j = threadIdx.x; j < 128; j += 64) {
        f4 v = src[j];
        sh4 o; o[0]=f2bf(v[0]); o[1]=f2bf(v[1]); o[2]=f2bf(v[2]); o[3]=f2bf(v[3]);
        dst[j] = o;
    }
}

// ---------------------------------------------------------------------------
// lstm_chain: COMM-FREE persistent BiLSTM. 16 blocks x 1024 thr (16 waves).
// Block owns 16 m-rows x FULL 256 hidden for one direction: whh entirely in
// VGPRs (128/lane), h(t) exchanged through a 16KB double-buffered LDS
// transpose buffer. No inter-block sync of any kind.
__global__ __launch_bounds__(1024)
void lstm_chain(const float* __restrict__ xfb,   // [32][128][2048] gates
                const short* __restrict__ whhf_b, const short* __restrict__ whhb_b,
                short* __restrict__ xcatb) {     // [32][128][1024]
    __shared__ short hbuf[2][16 * 256];          // 16 KB, swizzled
    const int blk = blockIdx.x;                  // 16 blocks
    const int dir = blk >> 3;
    const int m0  = (blk & 7) * 16;
    const short* whh = dir ? whhb_b : whhf_b;
    const int dcol = dir ? 256 : 0;

    const int tid = threadIdx.x, w4 = tid >> 6, lane = tid & 63;
    const int r = lane & 15, hh = lane >> 4;
    const int u = w4 * 16 + r;                   // this lane's hidden index

    // preload the full recurrent weight slice: 4 gates x 8 K-frags = 128 VGPR
    sh8 breg[4][8];
    #pragma unroll
    for (int g = 0; g < 4; g++) {
        const short* wrow = whh + ((size_t)(g * 256 + u)) * 256 + hh * 8;
        #pragma unroll
        for (int kk = 0; kk < 8; kk++) breg[g][kk] = *(const sh8*)(wrow + kk * 32);
    }

    float c_state[4] = {0.f, 0.f, 0.f, 0.f};

    for (int s = 0; s < 32; s++) {
        const int t = dir ? (31 - s) : s;
        // x-gates (independent of h; issued before the barrier, drain under it)
        float xv[4][4];
        #pragma unroll
        for (int g = 0; g < 4; g++)
            #pragma unroll
            for (int reg = 0; reg < 4; reg++)
                xv[g][reg] = xfb[((size_t)t * 128 + m0 + hh * 4 + reg) * 2048
                                 + dir * 1024 + g * 256 + u];
        f4 acc[4] = {};
        if (s > 0) {
            __syncthreads();                     // h(s-1) writes visible block-wide
            const char* hb = (const char*)&hbuf[(s - 1) & 1][0];
            #pragma unroll
            for (int kk = 0; kk < 8; kk++) {
                sh8 af = *(const sh8*)(hb + r * 512 +
                          ((kk * 64 + hh * 16) ^ ((r & 7) << 4)));
                #pragma unroll
                for (int g = 0; g < 4; g++)
                    acc[g] = __builtin_amdgcn_mfma_f32_16x16x32_bf16(af, breg[g][kk], acc[g], 0, 0, 0);
            }
        }
        char* hw = (char*)&hbuf[s & 1][0];
        #pragma unroll
        for (int reg = 0; reg < 4; reg++) {
            int row = hh * 4 + reg;              // block-local m row
            float gI = acc[0][reg] + xv[0][reg];
            float gF = acc[1][reg] + xv[1][reg];
            float gG = acc[2][reg] + xv[2][reg];
            float gO = acc[3][reg] + xv[3][reg];
            float cn = sigm(gF) * c_state[reg] + sigm(gI) * tanha(gG);
            c_state[reg] = cn;
            float h = sigm(gO) * tanha(cn);
            short hbv = f2bf(h);
            xcatb[((size_t)t * 128 + m0 + row) * 1024 + dcol + u] = hbv;  // global (plain)
            *(short*)(hw + row * 512 + ((u * 2) ^ ((row & 7) << 4))) = hbv;
        }
        // next iteration's __syncthreads separates these writes from reads
    }
}

// ---------------------------------------------------------------------------
// gru_chain: persistent GRU (R8-proven). 128 blocks x 128 thr.
// blk: mg=blk>>4 (16-row slice), ug=blk&15 (32-u slice). Group mg = 16 blocks.
// Weights 96KB dynamic LDS; agent-scope flag barrier; prefetch after signal.
__global__ __launch_bounds__(128)
void gru_chain(const float* __restrict__ gi,     // [32][128][1536] (incl b_ih)
               const short* __restrict__ gwhh_b, const float* __restrict__ bhh,
               short* __restrict__ gresb,        // [32][128][512]
               int* __restrict__ flags) {        // [8 grp][16 blk][16]
    extern __shared__ short wlds[];              // 96KB: 96 cols x 512 K
    const int blk = blockIdx.x;
    const int mg = blk >> 4, ug = blk & 15;
    const int m0 = mg * 16, u0 = ug * 32;

    int* grp_flags = flags + mg * 16 * 16;
    int* my_flag   = grp_flags + ug * 16;

    const int tid = threadIdx.x, w = tid >> 6, lane = tid & 63;
    const int r = lane & 15, hh = lane >> 4;
    unsigned* gres32 = (unsigned*)gresb;

    // stage weights once: 96 cols (g*32+ul) x 1024B, swizzled
    for (int i = 0; i < 48; i++) {
        int c = i * 128 + tid;
        int col = c >> 6, off = c & 63;
        int g = col >> 5, ul = col & 31;
        sh8 v = *(const sh8*)(gwhh_b + ((size_t)(g * 512 + u0 + ul)) * 512 + off * 8);
        *(sh8*)((char*)wlds + col * 1024 + ((off * 16) ^ ((col & 7) << 4))) = v;
    }
    __syncthreads();

    const int mb = m0 + hh * 4;
    const int u = u0 + w * 16 + r;
    const float bh_r = bhh[u], bh_z = bhh[512 + u], bh_n = bhh[1024 + u];
    float h_state[4] = {0.f, 0.f, 0.f, 0.f};

    float gv[3][4];
    #pragma unroll
    for (int g = 0; g < 3; g++)
        #pragma unroll
        for (int reg = 0; reg < 4; reg++)
            gv[g][reg] = gi[((size_t)(mb + reg)) * 1536 + g * 512 + u];

    for (int t = 0; t < 32; t++) {
        f4 acc[3] = {};
        if (t > 0) {
            grp_wait(grp_flags, 16, t);
            const short* arow = gresb + ((size_t)(t - 1) * 128 + m0 + r) * 512 + hh * 8;
            u4 afr[16];
            #pragma unroll
            for (int kk = 0; kk < 16; kk++) afr[kk] = cload_u4(arow + kk * 32);
            asm volatile("s_waitcnt vmcnt(0)" ::: "memory");
            __builtin_amdgcn_sched_barrier(0);
            #pragma unroll
            for (int kk = 0; kk < 16; kk++) {
                sh8 af = as_sh8(afr[kk]);
                #pragma unroll
                for (int g = 0; g < 3; g++) {
                    int colr = g * 32 + w * 16 + r;
                    sh8 bf = *(const sh8*)((const char*)wlds + colr * 1024 +
                              ((kk * 64 + hh * 16) ^ ((colr & 7) << 4)));
                    acc[g] = __builtin_amdgcn_mfma_f32_16x16x32_bf16(af, bf, acc[g], 0, 0, 0);
                }
            }
        }
        #pragma unroll
        for (int reg = 0; reg < 4; reg++) {
            int m = mb + reg;
            float rr = sigm(gv[0][reg] + acc[0][reg] + bh_r);
            float zz = sigm(gv[1][reg] + acc[1][reg] + bh_z);
            float nn = tanha(gv[2][reg] + rr * (acc[2][reg] + bh_n));
            float h = (1.f - zz) * nn + zz * h_state[reg];
            h_state[reg] = h;
            unsigned hb = (unsigned)(unsigned short)f2bf(h);
            unsigned pb = (unsigned)__shfl_xor((int)hb, 1, 64);
            if (!(r & 1))
                __hip_atomic_store(&gres32[((size_t)t * 128 + m) * 256 + (u >> 1)],
                                   hb | (pb << 16), __ATOMIC_RELAXED, __HIP_MEMORY_SCOPE_AGENT);
        }
        if (t < 31) {
            grp_signal(my_flag, t + 1);
            #pragma unroll
            for (int g = 0; g < 3; g++)
                #pragma unroll
                for (int reg = 0; reg < 4; reg++)
                    gv[g][reg] = gi[((size_t)(t + 1) * 128 + mb + reg) * 1536 + g * 512 + u];
        }
    }
}

// ---------------------------------------------------------------------------
extern "C" void kernel_launch(void* const* d_in, const int* in_sizes, int n_in,
                              void* d_out, int out_size, void* d_ws, size_t ws_size,
                              hipStream_t stream) {
    const float* feature = (const float*)d_in[0];
    const float* attmap  = (const float*)d_in[1];
    const int*   text    = (const int*)d_in[2];
    const float* cemb    = (const float*)d_in[4];
    const float* wihf    = (const float*)d_in[5];
    const float* whhf    = (const float*)d_in[6];
    const float* bihf    = (const float*)d_in[7];
    const float* bhhf    = (const float*)d_in[8];
    const float* wihb    = (const float*)d_in[9];
    const float* whhb    = (const float*)d_in[10];
    const float* bihb    = (const float*)d_in[11];
    const float* bhhb    = (const float*)d_in[12];
    const float* gwih    = (const float*)d_in[13];
    const float* gwhh    = (const float*)d_in[14];
    const float* gbih    = (const float*)d_in[15];
    const float* gbhh    = (const float*)d_in[16];
    const float* genw    = (const float*)d_in[17];
    const float* genb    = (const float*)d_in[18];

    float* out    = (float*)d_out;
    float* outAtt = out + (size_t)4096 * 6625;

    // workspace layout
    float* xfb   = (float*)d_ws;               // [32*128][2048] fwd|bwd gates
    float* gi    = xfb + 8388608;              // [32*128][1536]
    float* biasL = gi + 6291456;               // [2048]
    int*   flags = (int*)(biasL + 2048);       // [4096] (GRU uses [2048])
    short* cseqb  = (short*)(flags + 4096);
    short* xcatb  = cseqb + 2097152;
    short* gresb  = xcatb + 4194304;
    short* wih_b  = gresb + 2097152;
    short* whhf_b = wih_b + 1048576;
    short* whhb_b = whhf_b + 262144;
    short* gwih_b = whhb_b + 262144;
    short* gwhh_b = gwih_b + 1572864;
    short* genw_b = gwhh_b + 786432;

    hipFuncSetAttribute((const void*)gru_chain,
                        hipFuncAttributeMaxDynamicSharedMemorySize, 98304);

    zero_ctr<<<dim3(16), dim3(256), 0, stream>>>(flags, 4096);

    CvtPack p;
    p.s[0] = wihf; p.d[0] = wih_b;           p.n4[0] = 524288 / 4;
    p.s[1] = wihb; p.d[1] = wih_b + 524288;  p.n4[1] = 524288 / 4;
    p.s[2] = whhf; p.d[2] = whhf_b;          p.n4[2] = 262144 / 4;
    p.s[3] = whhb; p.d[3] = whhb_b;          p.n4[3] = 262144 / 4;
    p.s[4] = gwih; p.d[4] = gwih_b;          p.n4[4] = 1572864 / 4;
    p.s[5] = gwhh; p.d[5] = gwhh_b;          p.n4[5] = 786432 / 4;
    p.s[6] = genw; p.d[6] = genw_b;          p.n4[6] = 3392000 / 4;
    cvt_bf16<<<dim3(128, 7), dim3(256), 0, stream>>>(p);
    bias_prep<<<dim3(8), dim3(256), 0, stream>>>(bihf, bhhf, bihb, bhhb, biasL);

    att_norm<<<dim3(4096), dim3(64), 0, stream>>>(attmap, outAtt);
    pool_gemm<<<dim3(8, 128), dim3(256), 0, stream>>>(feature, outAtt, cseqb);

    // LSTM input gates (merged fwd+bwd): xfb = cseq @ [wihf;wihb]^T + biasL
    gemm128<0><<<dim3(32, 16), dim3(256), 0, stream>>>(cseqb, wih_b, biasL, nullptr,
                                                       xfb, 4096, 2048, 512);
    emb_fill<<<dim3(4096), dim3(64), 0, stream>>>(text, cemb, xcatb);

    lstm_chain<<<dim3(16), dim3(1024), 0, stream>>>(xfb, whhf_b, whhb_b, xcatb);

    gemm128<0><<<dim3(32, 12), dim3(256), 0, stream>>>(xcatb, gwih_b, gbih, nullptr,
                                                       gi, 4096, 1536, 1024);

    gru_chain<<<dim3(128), dim3(128), 98304, stream>>>(gi, gwhh_b, gbhh, gresb, flags);

    gemm128<1><<<dim3(32, 52), dim3(256), 0, stream>>>(gresb, genw_b, genb, nullptr,
                                                       out, 4096, 6625, 512);
}

// Round 12
// 548.233 us; speedup vs baseline: 1.0616x; 1.0616x over previous
//
#include <hip/hip_runtime.h>
#include <math.h>

typedef __attribute__((ext_vector_type(8))) short sh8;
typedef __attribute__((ext_vector_type(4))) short sh4;
typedef __attribute__((ext_vector_type(4))) float f4;
typedef __attribute__((ext_vector_type(4))) unsigned u4;

__device__ inline short f2bf(float f) {
    union { float f; unsigned u; } v; v.f = f;
    unsigned u = v.u;
    return (short)((u + 0x7fffu + ((u >> 16) & 1u)) >> 16);   // RNE
}
__device__ inline sh8 as_sh8(u4 v) { union { u4 u; sh8 s; } c; c.u = v; return c.s; }

// fast activations: native exp2/rcp, err ~1e-6
__device__ inline float sigm(float x)  { return __builtin_amdgcn_rcpf(1.f + __builtin_amdgcn_exp2f(-1.44269504f * x)); }
__device__ inline float tanha(float x) { return 1.f - 2.f * __builtin_amdgcn_rcpf(1.f + __builtin_amdgcn_exp2f(2.88539008f * x)); }

__device__ inline sh8 frag8(const float* __restrict__ p) {
    f4 a = *(const f4*)p;
    f4 b = *(const f4*)(p + 4);
    sh8 r;
    r[0]=f2bf(a[0]); r[1]=f2bf(a[1]); r[2]=f2bf(a[2]); r[3]=f2bf(a[3]);
    r[4]=f2bf(b[0]); r[5]=f2bf(b[1]); r[6]=f2bf(b[2]); r[7]=f2bf(b[3]);
    return r;
}

// Coherent 16B load: bypasses L1/L2, reads device coherence point (IF$).
__device__ inline u4 cload_u4(const void* p) {
    u4 r;
    asm volatile("global_load_dwordx4 %0, %1, off sc0 sc1" : "=v"(r) : "v"(p));
    return r;
}

// Group barrier (per-block 64B flag slots, monotonic epochs) — R8 proven form.
__device__ inline void grp_signal(int* myflag, int epoch) {
    asm volatile("s_waitcnt vmcnt(0)" ::: "memory");   // h-stores at coherence point
    __builtin_amdgcn_sched_barrier(0);
    __syncthreads();
    if (threadIdx.x == 0)
        __hip_atomic_store(myflag, epoch, __ATOMIC_RELAXED, __HIP_MEMORY_SCOPE_AGENT);
}
__device__ inline void grp_wait(const int* fbase, int nb, int epoch) {
    if (threadIdx.x < 64) {
        int lane = threadIdx.x;
        bool need = lane < nb;
        const int* fp = fbase + lane * 16;
        while (true) {
            int v = need ? __hip_atomic_load(fp, __ATOMIC_RELAXED, __HIP_MEMORY_SCOPE_AGENT)
                         : 0x7fffffff;
            if (__ballot(need && (v < epoch)) == 0ull) break;
            __builtin_amdgcn_s_sleep(1);
        }
    }
    __syncthreads();
}

// ---------------------------------------------------------------------------
__global__ void zero_ctr(int* c, int n) {
    int i = blockIdx.x * blockDim.x + threadIdx.x;
    if (i < n) c[i] = 0;
}

// ---------------------------------------------------------------------------
struct CvtPack { const float* s[7]; short* d[7]; int n4[7]; };
__global__ void cvt_bf16(CvtPack p) {
    int job = blockIdx.y;
    const f4* s = (const f4*)p.s[job];
    sh4* d = (sh4*)p.d[job];
    int n4 = p.n4[job];
    for (int i = blockIdx.x * blockDim.x + threadIdx.x; i < n4; i += gridDim.x * blockDim.x) {
        f4 v = s[i];
        sh4 o; o[0]=f2bf(v[0]); o[1]=f2bf(v[1]); o[2]=f2bf(v[2]); o[3]=f2bf(v[3]);
        d[i] = o;
    }
}

__global__ void bias_prep(const float* bihf, const float* bhhf,
                          const float* bihb, const float* bhhb, float* biasL) {
    int n = blockIdx.x * blockDim.x + threadIdx.x;
    biasL[n] = (n < 1024) ? bihf[n] + bhhf[n] : bihb[n - 1024] + bhhb[n - 1024];
}

// ---------------------------------------------------------------------------
__global__ void att_norm(const float* __restrict__ att, float* __restrict__ outA) {
    int row = blockIdx.x;
    int tid = threadIdx.x;
    const float* p = att + (size_t)row * 256;
    f4 v = *(const f4*)(p + tid * 4);
    float sum = v[0] + v[1] + v[2] + v[3];
    #pragma unroll
    for (int off = 32; off; off >>= 1) sum += __shfl_down(sum, off);
    float inv = 1.f / __shfl(sum, 0);
    f4 o; o[0]=v[0]*inv; o[1]=v[1]*inv; o[2]=v[2]*inv; o[3]=v[3]*inv;
    *(f4*)(outA + (size_t)row * 256 + tid * 4) = o;
}

// ---------------------------------------------------------------------------
__global__ __launch_bounds__(256)
void pool_gemm(const float* __restrict__ feature, const float* __restrict__ att,
               short* __restrict__ cseqb) {
    int bz = blockIdx.y;
    const float* A  = feature + (size_t)bz * 512 * 256;
    const float* Wt = att + (size_t)bz * 32 * 256;
    int wave = threadIdx.x >> 6, lane = threadIdx.x & 63, r = lane & 15, hh = lane >> 4;
    int m0 = blockIdx.x * 64 + wave * 16;
    f4 acc[2] = {};
    const float* ar = A  + (size_t)(m0 + r) * 256 + hh * 8;
    const float* w0 = Wt + (size_t)r * 256 + hh * 8;
    const float* w1 = Wt + (size_t)(16 + r) * 256 + hh * 8;
    for (int kk = 0; kk < 256; kk += 32) {
        sh8 af = frag8(ar + kk);
        acc[0] = __builtin_amdgcn_mfma_f32_16x16x32_bf16(af, frag8(w0 + kk), acc[0], 0, 0, 0);
        acc[1] = __builtin_amdgcn_mfma_f32_16x16x32_bf16(af, frag8(w1 + kk), acc[1], 0, 0, 0);
    }
    #pragma unroll
    for (int j = 0; j < 2; j++) {
        int t = j * 16 + r;
        #pragma unroll
        for (int reg = 0; reg < 4; reg++) {
            int c = m0 + hh * 4 + reg;
            cseqb[(size_t)t * 65536 + (size_t)bz * 512 + c] = f2bf(acc[j][reg]);
        }
    }
}

// ---------------------------------------------------------------------------
// gemm128: C[M,N] = A[M,K] @ W[N,K]^T + bias. bf16 operands, fp32 out.
template<int MODE>
__global__ __launch_bounds__(256)
void gemm128(const short* __restrict__ A, const short* __restrict__ W,
             const float* __restrict__ bias1, const float* __restrict__ bias2,
             float* __restrict__ out, int M, int N, int K) {
    __shared__ short lds[2][2][4096];
    const int tid = threadIdx.x, wave = tid >> 6, lane = tid & 63;
    const int r = lane & 15, hh = lane >> 4;
    const int wm = wave >> 1, wn = wave & 1;
    const int m0 = blockIdx.x * 128, n0 = blockIdx.y * 128;

    const int c0 = tid, c1 = 256 + tid;
    const int r0 = c0 >> 2, r1 = c1 >> 2;
    const int s0 = ((c0 & 3) ^ ((r0 >> 1) & 3));
    const int s1 = ((c1 & 3) ^ ((r1 >> 1) & 3));
    const short* gA0 = A + (size_t)(m0 + r0) * K + s0 * 8;
    const short* gA1 = A + (size_t)(m0 + r1) * K + s1 * 8;
    int wr0 = n0 + r0; if (wr0 > N - 1) wr0 = N - 1;
    int wr1 = n0 + r1; if (wr1 > N - 1) wr1 = N - 1;
    const short* gW0 = W + (size_t)wr0 * K + s0 * 8;
    const short* gW1 = W + (size_t)wr1 * K + s1 * 8;
    const int lo0 = (wave * 64) * 8, lo1 = (256 + wave * 64) * 8;

    auto stage = [&](int buf, int kt) {
        int ko = kt * 32;
        __builtin_amdgcn_global_load_lds((const __attribute__((address_space(1))) void*)(gA0 + ko),
            (__attribute__((address_space(3))) void*)&lds[buf][0][lo0], 16, 0, 0);
        __builtin_amdgcn_global_load_lds((const __attribute__((address_space(1))) void*)(gA1 + ko),
            (__attribute__((address_space(3))) void*)&lds[buf][0][lo1], 16, 0, 0);
        __builtin_amdgcn_global_load_lds((const __attribute__((address_space(1))) void*)(gW0 + ko),
            (__attribute__((address_space(3))) void*)&lds[buf][1][lo0], 16, 0, 0);
        __builtin_amdgcn_global_load_lds((const __attribute__((address_space(1))) void*)(gW1 + ko),
            (__attribute__((address_space(3))) void*)&lds[buf][1][lo1], 16, 0, 0);
    };

    f4 acc[4][4] = {};
    const int NT = K / 32;
    int cur = 0;

    stage(0, 0);
    __syncthreads();
    for (int kt = 0; kt < NT; ++kt) {
        if (kt + 1 < NT) stage(cur ^ 1, kt + 1);
        const char* As = (const char*)&lds[cur][0][0];
        const char* Ws = (const char*)&lds[cur][1][0];
        sh8 a[4], b[4];
        #pragma unroll
        for (int i = 0; i < 4; i++) {
            int row = wm * 64 + i * 16 + r;
            a[i] = *(const sh8*)(As + row * 64 + ((hh ^ ((row >> 1) & 3)) * 16));
        }
        #pragma unroll
        for (int i = 0; i < 4; i++) {
            int row = wn * 64 + i * 16 + r;
            b[i] = *(const sh8*)(Ws + row * 64 + ((hh ^ ((row >> 1) & 3)) * 16));
        }
        #pragma unroll
        for (int i = 0; i < 4; i++)
            #pragma unroll
            for (int j = 0; j < 4; j++)
                acc[i][j] = __builtin_amdgcn_mfma_f32_16x16x32_bf16(a[i], b[j], acc[i][j], 0, 0, 0);
        __syncthreads();
        cur ^= 1;
    }

    float bsj[4];
    #pragma unroll
    for (int j = 0; j < 4; j++) {
        int n = n0 + wn * 64 + j * 16 + r;
        int nc = n < N ? n : N - 1;
        bsj[j] = (bias1 ? bias1[nc] : 0.f) + (bias2 ? bias2[nc] : 0.f);
    }

    float* fl = (float*)&lds[0][0][0];
    #pragma unroll
    for (int hhalf = 0; hhalf < 2; hhalf++) {
        __syncthreads();
        if (wm == hhalf) {
            #pragma unroll
            for (int i = 0; i < 4; i++)
                #pragma unroll
                for (int j = 0; j < 4; j++) {
                    int col = wn * 64 + j * 16 + r;
                    #pragma unroll
                    for (int reg = 0; reg < 4; reg++)
                        fl[(i * 16 + hh * 4 + reg) * 128 + col] = acc[i][j][reg] + bsj[j];
                }
        }
        __syncthreads();
        #pragma unroll
        for (int it = 0; it < 8; it++) {
            int c = it * 256 + tid;
            int row = c >> 5, cf4 = c & 31;
            int n = n0 + cf4 * 4;
            int mrow = m0 + hhalf * 64 + row;
            size_t orow = (MODE == 0) ? (size_t)mrow
                                      : ((size_t)(mrow & 127) * 32 + (mrow >> 7));
            if (n + 3 < N) {
                *(f4*)&out[orow * N + n] = *(const f4*)&fl[row * 128 + cf4 * 4];
            } else {
                #pragma unroll
                for (int d = 0; d < 4; d++)
                    if (n + d < N) out[orow * N + n + d] = fl[row * 128 + cf4 * 4 + d];
            }
        }
    }
}

// ---------------------------------------------------------------------------
__global__ void emb_fill(const int* __restrict__ text, const float* __restrict__ emb,
                         short* __restrict__ xcatb) {
    int n = blockIdx.x;
    int t = n >> 7, b = n & 127;
    int idx = (t == 0) ? 0 : text[b * 32 + (t - 1)];
    const f4* src = (const f4*)(emb + (size_t)idx * 512);
    sh4* dst = (sh4*)(xcatb + (size_t)n * 1024 + 512);
    for (int j = threadIdx.x; j < 128; j += 64) {
        f4 v = src[j];
        sh4 o; o[0]=f2bf(v[0]); o[1]=f2bf(v[1]); o[2]=f2bf(v[2]); o[3]=f2bf(v[3]);
        dst[j] = o;
    }
}

// ---------------------------------------------------------------------------
// lstm_chain: persistent BiLSTM, fwd+bwd INTERLEAVED per block. 64 blocks x
// 128 thr. blk: mg=blk>>3 (16-row slice), ug=blk&7 (32-u slice). Block runs
// both directions for (mg,ug); each chain's barrier wait is hidden under the
// other chain's compute. Weights 2x64KB dynamic LDS. R8 protocol per chain.
__global__ __launch_bounds__(128)
void lstm_chain(const float* __restrict__ xfb,   // [32][128][2048] gates
                const short* __restrict__ whhf_b, const short* __restrict__ whhb_b,
                short* __restrict__ xcatb,       // [32][128][1024]
                int* __restrict__ flags) {       // [16 grp][8 blk][16]
    extern __shared__ short wlds[];              // 128KB: [dir][128 cols][512B]
    const int blk = blockIdx.x;
    const int mg = blk >> 3, ug = blk & 7;
    const int m0 = mg * 16, u0 = ug * 32;

    int* gfF = flags + (0 * 8 + mg) * 128;       // fwd group flags (8 members)
    int* gfB = flags + (1 * 8 + mg) * 128;       // bwd group flags
    int* myF = gfF + ug * 16;
    int* myB = gfB + ug * 16;

    const int tid = threadIdx.x, w = tid >> 6, lane = tid & 63;
    const int r = lane & 15, hh = lane >> 4;
    unsigned* xcat32 = (unsigned*)xcatb;

    // stage both directions' weight slices: per dir 128 cols (g*32+ul) x 512B
    #pragma unroll
    for (int d = 0; d < 2; d++) {
        const short* whh = d ? whhb_b : whhf_b;
        for (int i = 0; i < 32; i++) {
            int c = i * 128 + tid;               // 4096 chunks of 16B
            int col = c >> 5, off = c & 31;
            int g = col >> 5, ul = col & 31;
            sh8 v = *(const sh8*)(whh + ((size_t)(g * 256 + u0 + ul)) * 256 + off * 8);
            *(sh8*)((char*)wlds + d * 65536 + col * 512 + ((off * 16) ^ ((col & 7) << 4))) = v;
        }
    }
    __syncthreads();

    const int mb = m0 + hh * 4;
    const int u = u0 + w * 16 + r;
    float c_f[4] = {}, c_b[4] = {};

    // preload step-0 x-gates for both chains
    float xvF[4][4], xvB[4][4];
    #pragma unroll
    for (int g = 0; g < 4; g++)
        #pragma unroll
        for (int reg = 0; reg < 4; reg++) {
            xvF[g][reg] = xfb[((size_t)0 * 128 + mb + reg) * 2048 + 0 + g * 256 + u];
            xvB[g][reg] = xfb[((size_t)31 * 128 + mb + reg) * 2048 + 1024 + g * 256 + u];
        }

    for (int s = 0; s < 32; s++) {
        // ---- chain F (dir 0, t = s) ----
        {
            const int t = s;
            f4 acc[4] = {};
            if (s > 0) {
                grp_wait(gfF, 8, s);
                const short* arow = xcatb + ((size_t)(t - 1) * 128 + m0 + r) * 1024 + 0 + hh * 8;
                u4 afr[8];
                #pragma unroll
                for (int kk = 0; kk < 8; kk++) afr[kk] = cload_u4(arow + kk * 32);
                asm volatile("s_waitcnt vmcnt(0)" ::: "memory");
                __builtin_amdgcn_sched_barrier(0);
                #pragma unroll
                for (int kk = 0; kk < 8; kk++) {
                    sh8 af = as_sh8(afr[kk]);
                    #pragma unroll
                    for (int g = 0; g < 4; g++) {
                        int colr = g * 32 + w * 16 + r;
                        sh8 bf = *(const sh8*)((const char*)wlds + colr * 512 +
                                  ((kk * 64 + hh * 16) ^ ((colr & 7) << 4)));
                        acc[g] = __builtin_amdgcn_mfma_f32_16x16x32_bf16(af, bf, acc[g], 0, 0, 0);
                    }
                }
            }
            #pragma unroll
            for (int reg = 0; reg < 4; reg++) {
                int m = mb + reg;
                float gI = acc[0][reg] + xvF[0][reg];
                float gF = acc[1][reg] + xvF[1][reg];
                float gG = acc[2][reg] + xvF[2][reg];
                float gO = acc[3][reg] + xvF[3][reg];
                float cn = sigm(gF) * c_f[reg] + sigm(gI) * tanha(gG);
                c_f[reg] = cn;
                float h = sigm(gO) * tanha(cn);
                unsigned hb = (unsigned)(unsigned short)f2bf(h);
                unsigned pb = (unsigned)__shfl_xor((int)hb, 1, 64);
                if (!(r & 1))
                    __hip_atomic_store(&xcat32[((size_t)t * 128 + m) * 512 + (u >> 1)],
                                       hb | (pb << 16), __ATOMIC_RELAXED, __HIP_MEMORY_SCOPE_AGENT);
            }
            if (s < 31) {
                grp_signal(myF, s + 1);
                #pragma unroll
                for (int g = 0; g < 4; g++)
                    #pragma unroll
                    for (int reg = 0; reg < 4; reg++)
                        xvF[g][reg] = xfb[((size_t)(t + 1) * 128 + mb + reg) * 2048 + g * 256 + u];
            }
        }
        // ---- chain B (dir 1, t = 31 - s) ----
        {
            const int t = 31 - s;
            f4 acc[4] = {};
            if (s > 0) {
                grp_wait(gfB, 8, s);
                const short* arow = xcatb + ((size_t)(t + 1) * 128 + m0 + r) * 1024 + 256 + hh * 8;
                u4 afr[8];
                #pragma unroll
                for (int kk = 0; kk < 8; kk++) afr[kk] = cload_u4(arow + kk * 32);
                asm volatile("s_waitcnt vmcnt(0)" ::: "memory");
                __builtin_amdgcn_sched_barrier(0);
                #pragma unroll
                for (int kk = 0; kk < 8; kk++) {
                    sh8 af = as_sh8(afr[kk]);
                    #pragma unroll
                    for (int g = 0; g < 4; g++) {
                        int colr = g * 32 + w * 16 + r;
                        sh8 bf = *(const sh8*)((const char*)wlds + 65536 + colr * 512 +
                                  ((kk * 64 + hh * 16) ^ ((colr & 7) << 4)));
                        acc[g] = __builtin_amdgcn_mfma_f32_16x16x32_bf16(af, bf, acc[g], 0, 0, 0);
                    }
                }
            }
            #pragma unroll
            for (int reg = 0; reg < 4; reg++) {
                int m = mb + reg;
                float gI = acc[0][reg] + xvB[0][reg];
                float gF = acc[1][reg] + xvB[1][reg];
                float gG = acc[2][reg] + xvB[2][reg];
                float gO = acc[3][reg] + xvB[3][reg];
                float cn = sigm(gF) * c_b[reg] + sigm(gI) * tanha(gG);
                c_b[reg] = cn;
                float h = sigm(gO) * tanha(cn);
                unsigned hb = (unsigned)(unsigned short)f2bf(h);
                unsigned pb = (unsigned)__shfl_xor((int)hb, 1, 64);
                if (!(r & 1))
                    __hip_atomic_store(&xcat32[((size_t)t * 128 + m) * 512 + 128 + (u >> 1)],
                                       hb | (pb << 16), __ATOMIC_RELAXED, __HIP_MEMORY_SCOPE_AGENT);
            }
            if (s < 31) {
                grp_signal(myB, s + 1);
                #pragma unroll
                for (int g = 0; g < 4; g++)
                    #pragma unroll
                    for (int reg = 0; reg < 4; reg++)
                        xvB[g][reg] = xfb[((size_t)(t - 1) * 128 + mb + reg) * 2048 + 1024 + g * 256 + u];
            }
        }
    }
}

// ---------------------------------------------------------------------------
// gru_chain: persistent GRU, TWO m-group chains per block (A: mg=p, B: mg=p+4)
// sharing one 96KB weight LDS. 64 blocks x 128 thr; group = 16 blocks per mg.
// Each chain's barrier wait hides under the other chain's compute. R8 protocol.
__global__ __launch_bounds__(128)
void gru_chain(const float* __restrict__ gi,     // [32][128][1536] (incl b_ih)
               const short* __restrict__ gwhh_b, const float* __restrict__ bhh,
               short* __restrict__ gresb,        // [32][128][512]
               int* __restrict__ flags) {        // [8 grp][16 blk][16]
    extern __shared__ short wlds[];              // 96KB: 96 cols x 1024B
    const int blk = blockIdx.x;
    const int p = blk >> 4, ug = blk & 15;
    const int m0A = p * 16, m0B = (p + 4) * 16;
    const int u0 = ug * 32;

    int* gfA = flags + p * 256;                  // group p flags (16 members)
    int* gfB = flags + (p + 4) * 256;
    int* myA = gfA + ug * 16;
    int* myB = gfB + ug * 16;

    const int tid = threadIdx.x, w = tid >> 6, lane = tid & 63;
    const int r = lane & 15, hh = lane >> 4;
    unsigned* gres32 = (unsigned*)gresb;

    // stage shared weights once: 96 cols (g*32+ul) x 1024B, swizzled
    for (int i = 0; i < 48; i++) {
        int c = i * 128 + tid;
        int col = c >> 6, off = c & 63;
        int g = col >> 5, ul = col & 31;
        sh8 v = *(const sh8*)(gwhh_b + ((size_t)(g * 512 + u0 + ul)) * 512 + off * 8);
        *(sh8*)((char*)wlds + col * 1024 + ((off * 16) ^ ((col & 7) << 4))) = v;
    }
    __syncthreads();

    const int mbA = m0A + hh * 4, mbB = m0B + hh * 4;
    const int u = u0 + w * 16 + r;
    const float bh_r = bhh[u], bh_z = bhh[512 + u], bh_n = bhh[1024 + u];
    float hA[4] = {}, hB[4] = {};

    float gvA[3][4], gvB[3][4];
    #pragma unroll
    for (int g = 0; g < 3; g++)
        #pragma unroll
        for (int reg = 0; reg < 4; reg++) {
            gvA[g][reg] = gi[((size_t)(mbA + reg)) * 1536 + g * 512 + u];
            gvB[g][reg] = gi[((size_t)(mbB + reg)) * 1536 + g * 512 + u];
        }

    for (int t = 0; t < 32; t++) {
        // ---- chain A ----
        {
            f4 acc[3] = {};
            if (t > 0) {
                grp_wait(gfA, 16, t);
                const short* arow = gresb + ((size_t)(t - 1) * 128 + m0A + r) * 512 + hh * 8;
                u4 afr[16];
                #pragma unroll
                for (int kk = 0; kk < 16; kk++) afr[kk] = cload_u4(arow + kk * 32);
                asm volatile("s_waitcnt vmcnt(0)" ::: "memory");
                __builtin_amdgcn_sched_barrier(0);
                #pragma unroll
                for (int kk = 0; kk < 16; kk++) {
                    sh8 af = as_sh8(afr[kk]);
                    #pragma unroll
                    for (int g = 0; g < 3; g++) {
                        int colr = g * 32 + w * 16 + r;
                        sh8 bf = *(const sh8*)((const char*)wlds + colr * 1024 +
                                  ((kk * 64 + hh * 16) ^ ((colr & 7) << 4)));
                        acc[g] = __builtin_amdgcn_mfma_f32_16x16x32_bf16(af, bf, acc[g], 0, 0, 0);
                    }
                }
            }
            #pragma unroll
            for (int reg = 0; reg < 4; reg++) {
                int m = mbA + reg;
                float rr = sigm(gvA[0][reg] + acc[0][reg] + bh_r);
                float zz = sigm(gvA[1][reg] + acc[1][reg] + bh_z);
                float nn = tanha(gvA[2][reg] + rr * (acc[2][reg] + bh_n));
                float h = (1.f - zz) * nn + zz * hA[reg];
                hA[reg] = h;
                unsigned hb = (unsigned)(unsigned short)f2bf(h);
                unsigned pb = (unsigned)__shfl_xor((int)hb, 1, 64);
                if (!(r & 1))
                    __hip_atomic_store(&gres32[((size_t)t * 128 + m) * 256 + (u >> 1)],
                                       hb | (pb << 16), __ATOMIC_RELAXED, __HIP_MEMORY_SCOPE_AGENT);
            }
            if (t < 31) {
                grp_signal(myA, t + 1);
                #pragma unroll
                for (int g = 0; g < 3; g++)
                    #pragma unroll
                    for (int reg = 0; reg < 4; reg++)
                        gvA[g][reg] = gi[((size_t)(t + 1) * 128 + mbA + reg) * 1536 + g * 512 + u];
            }
        }
        // ---- chain B ----
        {
            f4 acc[3] = {};
            if (t > 0) {
                grp_wait(gfB, 16, t);
                const short* arow = gresb + ((size_t)(t - 1) * 128 + m0B + r) * 512 + hh * 8;
                u4 afr[16];
                #pragma unroll
                for (int kk = 0; kk < 16; kk++) afr[kk] = cload_u4(arow + kk * 32);
                asm volatile("s_waitcnt vmcnt(0)" ::: "memory");
                __builtin_amdgcn_sched_barrier(0);
                #pragma unroll
                for (int kk = 0; kk < 16; kk++) {
                    sh8 af = as_sh8(afr[kk]);
                    #pragma unroll
                    for (int g = 0; g < 3; g++) {
                        int colr = g * 32 + w * 16 + r;
                        sh8 bf = *(const sh8*)((const char*)wlds + colr * 1024 +
                                  ((kk * 64 + hh * 16) ^ ((colr & 7) << 4)));
                        acc[g] = __builtin_amdgcn_mfma_f32_16x16x32_bf16(af, bf, acc[g], 0, 0, 0);
                    }
                }
            }
            #pragma unroll
            for (int reg = 0; reg < 4; reg++) {
                int m = mbB + reg;
                float rr = sigm(gvB[0][reg] + acc[0][reg] + bh_r);
                float zz = sigm(gvB[1][reg] + acc[1][reg] + bh_z);
                float nn = tanha(gvB[2][reg] + rr * (acc[2][reg] + bh_n));
                float h = (1.f - zz) * nn + zz * hB[reg];
                hB[reg] = h;
                unsigned hb = (unsigned)(unsigned short)f2bf(h);
                unsigned pb = (unsigned)__shfl_xor((int)hb, 1, 64);
                if (!(r & 1))
                    __hip_atomic_store(&gres32[((size_t)t * 128 + m) * 256 + (u >> 1)],
                                       hb | (pb << 16), __ATOMIC_RELAXED, __HIP_MEMORY_SCOPE_AGENT);
            }
            if (t < 31) {
                grp_signal(myB, t + 1);
                #pragma unroll
                for (int g = 0; g < 3; g++)
                    #pragma unroll
                    for (int reg = 0; reg < 4; reg++)
                        gvB[g][reg] = gi[((size_t)(t + 1) * 128 + mbB + reg) * 1536 + g * 512 + u];
            }
        }
    }
}

// ---------------------------------------------------------------------------
extern "C" void kernel_launch(void* const* d_in, const int* in_sizes, int n_in,
                              void* d_out, int out_size, void* d_ws, size_t ws_size,
                              hipStream_t stream) {
    const float* feature = (const float*)d_in[0];
    const float* attmap  = (const float*)d_in[1];
    const int*   text    = (const int*)d_in[2];
    const float* cemb    = (const float*)d_in[4];
    const float* wihf    = (const float*)d_in[5];
    const float* whhf    = (const float*)d_in[6];
    const float* bihf    = (const float*)d_in[7];
    const float* bhhf    = (const float*)d_in[8];
    const float* wihb    = (const float*)d_in[9];
    const float* whhb    = (const float*)d_in[10];
    const float* bihb    = (const float*)d_in[11];
    const float* bhhb    = (const float*)d_in[12];
    const float* gwih    = (const float*)d_in[13];
    const float* gwhh    = (const float*)d_in[14];
    const float* gbih    = (const float*)d_in[15];
    const float* gbhh    = (const float*)d_in[16];
    const float* genw    = (const float*)d_in[17];
    const float* genb    = (const float*)d_in[18];

    float* out    = (float*)d_out;
    float* outAtt = out + (size_t)4096 * 6625;

    // workspace layout
    float* xfb   = (float*)d_ws;               // [32*128][2048] fwd|bwd gates
    float* gi    = xfb + 8388608;              // [32*128][1536]
    float* biasL = gi + 6291456;               // [2048]
    int*   flags = (int*)(biasL + 2048);       // [4096]: LSTM [0,2048) GRU [2048,4096)
    short* cseqb  = (short*)(flags + 4096);
    short* xcatb  = cseqb + 2097152;
    short* gresb  = xcatb + 4194304;
    short* wih_b  = gresb + 2097152;
    short* whhf_b = wih_b + 1048576;
    short* whhb_b = whhf_b + 262144;
    short* gwih_b = whhb_b + 262144;
    short* gwhh_b = gwih_b + 1572864;
    short* genw_b = gwhh_b + 786432;

    hipFuncSetAttribute((const void*)lstm_chain,
                        hipFuncAttributeMaxDynamicSharedMemorySize, 131072);
    hipFuncSetAttribute((const void*)gru_chain,
                        hipFuncAttributeMaxDynamicSharedMemorySize, 98304);

    zero_ctr<<<dim3(16), dim3(256), 0, stream>>>(flags, 4096);

    CvtPack p;
    p.s[0] = wihf; p.d[0] = wih_b;           p.n4[0] = 524288 / 4;
    p.s[1] = wihb; p.d[1] = wih_b + 524288;  p.n4[1] = 524288 / 4;
    p.s[2] = whhf; p.d[2] = whhf_b;          p.n4[2] = 262144 / 4;
    p.s[3] = whhb; p.d[3] = whhb_b;          p.n4[3] = 262144 / 4;
    p.s[4] = gwih; p.d[4] = gwih_b;          p.n4[4] = 1572864 / 4;
    p.s[5] = gwhh; p.d[5] = gwhh_b;          p.n4[5] = 786432 / 4;
    p.s[6] = genw; p.d[6] = genw_b;          p.n4[6] = 3392000 / 4;
    cvt_bf16<<<dim3(128, 7), dim3(256), 0, stream>>>(p);
    bias_prep<<<dim3(8), dim3(256), 0, stream>>>(bihf, bhhf, bihb, bhhb, biasL);

    att_norm<<<dim3(4096), dim3(64), 0, stream>>>(attmap, outAtt);
    pool_gemm<<<dim3(8, 128), dim3(256), 0, stream>>>(feature, outAtt, cseqb);

    // LSTM input gates (merged fwd+bwd): xfb = cseq @ [wihf;wihb]^T + biasL
    gemm128<0><<<dim3(32, 16), dim3(256), 0, stream>>>(cseqb, wih_b, biasL, nullptr,
                                                       xfb, 4096, 2048, 512);
    emb_fill<<<dim3(4096), dim3(64), 0, stream>>>(text, cemb, xcatb);

    lstm_chain<<<dim3(64), dim3(128), 131072, stream>>>(xfb, whhf_b, whhb_b, xcatb, flags);

    gemm128<0><<<dim3(32, 12), dim3(256), 0, stream>>>(xcatb, gwih_b, gbih, nullptr,
                                                       gi, 4096, 1536, 1024);

    gru_chain<<<dim3(64), dim3(128), 98304, stream>>>(gi, gwhh_b, gbhh, gresb, flags + 2048);

    gemm128<1><<<dim3(32, 52), dim3(256), 0, stream>>>(gresb, genw_b, genb, nullptr,
                                                       out, 4096, 6625, 512);
}

// Round 13
// 385.673 us; speedup vs baseline: 1.5091x; 1.4215x over previous
//
#include <hip/hip_runtime.h>
#include <math.h>

typedef __attribute__((ext_vector_type(8))) short sh8;
typedef __attribute__((ext_vector_type(4))) short sh4;
typedef __attribute__((ext_vector_type(4))) float f4;
typedef __attribute__((ext_vector_type(4))) unsigned u4;

__device__ inline short f2bf(float f) {
    union { float f; unsigned u; } v; v.f = f;
    unsigned u = v.u;
    return (short)((u + 0x7fffu + ((u >> 16) & 1u)) >> 16);   // RNE
}
__device__ inline sh8 as_sh8(u4 v) { union { u4 u; sh8 s; } c; c.u = v; return c.s; }

// fast activations: native exp2/rcp, err ~1e-6 (validated R8-R12, absmax 0.0039)
__device__ inline float sigm(float x)  { return __builtin_amdgcn_rcpf(1.f + __builtin_amdgcn_exp2f(-1.44269504f * x)); }
__device__ inline float tanha(float x) { return 1.f - 2.f * __builtin_amdgcn_rcpf(1.f + __builtin_amdgcn_exp2f(2.88539008f * x)); }

__device__ inline sh8 frag8(const float* __restrict__ p) {
    f4 a = *(const f4*)p;
    f4 b = *(const f4*)(p + 4);
    sh8 r;
    r[0]=f2bf(a[0]); r[1]=f2bf(a[1]); r[2]=f2bf(a[2]); r[3]=f2bf(a[3]);
    r[4]=f2bf(b[0]); r[5]=f2bf(b[1]); r[6]=f2bf(b[2]); r[7]=f2bf(b[3]);
    return r;
}

// Coherent 16B load: bypasses L1/L2, reads device coherence point (IF$).
__device__ inline u4 cload_u4(const void* p) {
    u4 r;
    asm volatile("global_load_dwordx4 %0, %1, off sc0 sc1" : "=v"(r) : "v"(p));
    return r;
}

// Group barrier (per-block 64B flag slots, monotonic epochs) — R5/R8 proven.
__device__ inline void grp_signal(int* myflag, int epoch) {
    asm volatile("s_waitcnt vmcnt(0)" ::: "memory");   // h-stores at coherence point
    __builtin_amdgcn_sched_barrier(0);
    __syncthreads();
    if (threadIdx.x == 0)
        __hip_atomic_store(myflag, epoch, __ATOMIC_RELAXED, __HIP_MEMORY_SCOPE_AGENT);
}
__device__ inline void grp_wait(const int* fbase, int nb, int epoch) {
    if (threadIdx.x < 64) {
        int lane = threadIdx.x;
        bool need = lane < nb;
        const int* fp = fbase + lane * 16;
        while (true) {
            int v = need ? __hip_atomic_load(fp, __ATOMIC_RELAXED, __HIP_MEMORY_SCOPE_AGENT)
                         : 0x7fffffff;
            if (__ballot(need && (v < epoch)) == 0ull) break;
            __builtin_amdgcn_s_sleep(1);
        }
    }
    __syncthreads();
}

// ---------------------------------------------------------------------------
__global__ void zero_ctr(int* c, int n) {
    int i = blockIdx.x * blockDim.x + threadIdx.x;
    if (i < n) c[i] = 0;
}

// ---------------------------------------------------------------------------
struct CvtPack { const float* s[7]; short* d[7]; int n4[7]; };
__global__ void cvt_bf16(CvtPack p) {
    int job = blockIdx.y;
    const f4* s = (const f4*)p.s[job];
    sh4* d = (sh4*)p.d[job];
    int n4 = p.n4[job];
    for (int i = blockIdx.x * blockDim.x + threadIdx.x; i < n4; i += gridDim.x * blockDim.x) {
        f4 v = s[i];
        sh4 o; o[0]=f2bf(v[0]); o[1]=f2bf(v[1]); o[2]=f2bf(v[2]); o[3]=f2bf(v[3]);
        d[i] = o;
    }
}

__global__ void bias_prep(const float* bihf, const float* bhhf,
                          const float* bihb, const float* bhhb, float* biasL) {
    int n = blockIdx.x * blockDim.x + threadIdx.x;
    biasL[n] = (n < 1024) ? bihf[n] + bhhf[n] : bihb[n - 1024] + bhhb[n - 1024];
}

// ---------------------------------------------------------------------------
__global__ void att_norm(const float* __restrict__ att, float* __restrict__ outA) {
    int row = blockIdx.x;
    int tid = threadIdx.x;
    const float* p = att + (size_t)row * 256;
    f4 v = *(const f4*)(p + tid * 4);
    float sum = v[0] + v[1] + v[2] + v[3];
    #pragma unroll
    for (int off = 32; off; off >>= 1) sum += __shfl_down(sum, off);
    float inv = 1.f / __shfl(sum, 0);
    f4 o; o[0]=v[0]*inv; o[1]=v[1]*inv; o[2]=v[2]*inv; o[3]=v[3]*inv;
    *(f4*)(outA + (size_t)row * 256 + tid * 4) = o;
}

// ---------------------------------------------------------------------------
__global__ __launch_bounds__(256)
void pool_gemm(const float* __restrict__ feature, const float* __restrict__ att,
               short* __restrict__ cseqb) {
    int bz = blockIdx.y;
    const float* A  = feature + (size_t)bz * 512 * 256;
    const float* Wt = att + (size_t)bz * 32 * 256;
    int wave = threadIdx.x >> 6, lane = threadIdx.x & 63, r = lane & 15, hh = lane >> 4;
    int m0 = blockIdx.x * 64 + wave * 16;
    f4 acc[2] = {};
    const float* ar = A  + (size_t)(m0 + r) * 256 + hh * 8;
    const float* w0 = Wt + (size_t)r * 256 + hh * 8;
    const float* w1 = Wt + (size_t)(16 + r) * 256 + hh * 8;
    for (int kk = 0; kk < 256; kk += 32) {
        sh8 af = frag8(ar + kk);
        acc[0] = __builtin_amdgcn_mfma_f32_16x16x32_bf16(af, frag8(w0 + kk), acc[0], 0, 0, 0);
        acc[1] = __builtin_amdgcn_mfma_f32_16x16x32_bf16(af, frag8(w1 + kk), acc[1], 0, 0, 0);
    }
    #pragma unroll
    for (int j = 0; j < 2; j++) {
        int t = j * 16 + r;
        #pragma unroll
        for (int reg = 0; reg < 4; reg++) {
            int c = m0 + hh * 4 + reg;
            cseqb[(size_t)t * 65536 + (size_t)bz * 512 + c] = f2bf(acc[j][reg]);
        }
    }
}

// ---------------------------------------------------------------------------
// gemm128: C[M,N] = A[M,K] @ W[N,K]^T + bias. bf16 operands, fp32 out.
template<int MODE>
__global__ __launch_bounds__(256)
void gemm128(const short* __restrict__ A, const short* __restrict__ W,
             const float* __restrict__ bias1, const float* __restrict__ bias2,
             float* __restrict__ out, int M, int N, int K) {
    __shared__ short lds[2][2][4096];
    const int tid = threadIdx.x, wave = tid >> 6, lane = tid & 63;
    const int r = lane & 15, hh = lane >> 4;
    const int wm = wave >> 1, wn = wave & 1;
    const int m0 = blockIdx.x * 128, n0 = blockIdx.y * 128;

    const int c0 = tid, c1 = 256 + tid;
    const int r0 = c0 >> 2, r1 = c1 >> 2;
    const int s0 = ((c0 & 3) ^ ((r0 >> 1) & 3));
    const int s1 = ((c1 & 3) ^ ((r1 >> 1) & 3));
    const short* gA0 = A + (size_t)(m0 + r0) * K + s0 * 8;
    const short* gA1 = A + (size_t)(m0 + r1) * K + s1 * 8;
    int wr0 = n0 + r0; if (wr0 > N - 1) wr0 = N - 1;
    int wr1 = n0 + r1; if (wr1 > N - 1) wr1 = N - 1;
    const short* gW0 = W + (size_t)wr0 * K + s0 * 8;
    const short* gW1 = W + (size_t)wr1 * K + s1 * 8;
    const int lo0 = (wave * 64) * 8, lo1 = (256 + wave * 64) * 8;

    auto stage = [&](int buf, int kt) {
        int ko = kt * 32;
        __builtin_amdgcn_global_load_lds((const __attribute__((address_space(1))) void*)(gA0 + ko),
            (__attribute__((address_space(3))) void*)&lds[buf][0][lo0], 16, 0, 0);
        __builtin_amdgcn_global_load_lds((const __attribute__((address_space(1))) void*)(gA1 + ko),
            (__attribute__((address_space(3))) void*)&lds[buf][0][lo1], 16, 0, 0);
        __builtin_amdgcn_global_load_lds((const __attribute__((address_space(1))) void*)(gW0 + ko),
            (__attribute__((address_space(3))) void*)&lds[buf][1][lo0], 16, 0, 0);
        __builtin_amdgcn_global_load_lds((const __attribute__((address_space(1))) void*)(gW1 + ko),
            (__attribute__((address_space(3))) void*)&lds[buf][1][lo1], 16, 0, 0);
    };

    f4 acc[4][4] = {};
    const int NT = K / 32;
    int cur = 0;

    stage(0, 0);
    __syncthreads();
    for (int kt = 0; kt < NT; ++kt) {
        if (kt + 1 < NT) stage(cur ^ 1, kt + 1);
        const char* As = (const char*)&lds[cur][0][0];
        const char* Ws = (const char*)&lds[cur][1][0];
        sh8 a[4], b[4];
        #pragma unroll
        for (int i = 0; i < 4; i++) {
            int row = wm * 64 + i * 16 + r;
            a[i] = *(const sh8*)(As + row * 64 + ((hh ^ ((row >> 1) & 3)) * 16));
        }
        #pragma unroll
        for (int i = 0; i < 4; i++) {
            int row = wn * 64 + i * 16 + r;
            b[i] = *(const sh8*)(Ws + row * 64 + ((hh ^ ((row >> 1) & 3)) * 16));
        }
        #pragma unroll
        for (int i = 0; i < 4; i++)
            #pragma unroll
            for (int j = 0; j < 4; j++)
                acc[i][j] = __builtin_amdgcn_mfma_f32_16x16x32_bf16(a[i], b[j], acc[i][j], 0, 0, 0);
        __syncthreads();
        cur ^= 1;
    }

    float bsj[4];
    #pragma unroll
    for (int j = 0; j < 4; j++) {
        int n = n0 + wn * 64 + j * 16 + r;
        int nc = n < N ? n : N - 1;
        bsj[j] = (bias1 ? bias1[nc] : 0.f) + (bias2 ? bias2[nc] : 0.f);
    }

    float* fl = (float*)&lds[0][0][0];
    #pragma unroll
    for (int hhalf = 0; hhalf < 2; hhalf++) {
        __syncthreads();
        if (wm == hhalf) {
            #pragma unroll
            for (int i = 0; i < 4; i++)
                #pragma unroll
                for (int j = 0; j < 4; j++) {
                    int col = wn * 64 + j * 16 + r;
                    #pragma unroll
                    for (int reg = 0; reg < 4; reg++)
                        fl[(i * 16 + hh * 4 + reg) * 128 + col] = acc[i][j][reg] + bsj[j];
                }
        }
        __syncthreads();
        #pragma unroll
        for (int it = 0; it < 8; it++) {
            int c = it * 256 + tid;
            int row = c >> 5, cf4 = c & 31;
            int n = n0 + cf4 * 4;
            int mrow = m0 + hhalf * 64 + row;
            size_t orow = (MODE == 0) ? (size_t)mrow
                                      : ((size_t)(mrow & 127) * 32 + (mrow >> 7));
            if (n + 3 < N) {
                *(f4*)&out[orow * N + n] = *(const f4*)&fl[row * 128 + cf4 * 4];
            } else {
                #pragma unroll
                for (int d = 0; d < 4; d++)
                    if (n + d < N) out[orow * N + n + d] = fl[row * 128 + cf4 * 4 + d];
            }
        }
    }
}

// ---------------------------------------------------------------------------
__global__ void emb_fill(const int* __restrict__ text, const float* __restrict__ emb,
                         short* __restrict__ xcatb) {
    int n = blockIdx.x;
    int t = n >> 7, b = n & 127;
    int idx = (t == 0) ? 0 : text[b * 32 + (t - 1)];
    const f4* src = (const f4*)(emb + (size_t)idx * 512);
    sh4* dst = (sh4*)(xcatb + (size_t)n * 1024 + 512);
    for (int j = threadIdx.x; j < 128; j += 64) {
        f4 v = src[j];
        sh4 o; o[0]=f2bf(v[0]); o[1]=f2bf(v[1]); o[2]=f2bf(v[2]); o[3]=f2bf(v[3]);
        dst[j] = o;
    }
}

// ---------------------------------------------------------------------------
// lstm_chain: R5-proven form. 128 blocks x 128 thr (2 waves).
// blk: dir=blk>>6, mg=(blk>>4)&3 (32-row slice), ug=blk&15 (16-u slice).
// Group (dir,mg) = 16 blocks. 32KB static LDS. Prefetch after signal.
__global__ __launch_bounds__(128)
void lstm_chain(const float* __restrict__ xfb,   // [32][128][2048] gates
                const short* __restrict__ whhf_b, const short* __restrict__ whhb_b,
                short* __restrict__ xcatb,       // [32][128][1024]
                int* __restrict__ flags) {       // [8 grp][16 blk][16]
    __shared__ short wlds[64 * 256];             // 32KB
    const int blk = blockIdx.x;
    const int dir = blk >> 6;
    const int mg  = (blk >> 4) & 3;
    const int ug  = blk & 15;
    const int m0 = mg * 32, u0 = ug * 16;
    const short* whh = dir ? whhb_b : whhf_b;
    const int dcol = dir ? 256 : 0;

    int* grp_flags = flags + (dir * 4 + mg) * 16 * 16;
    int* my_flag   = grp_flags + ug * 16;

    const int tid = threadIdx.x, mt = tid >> 6, lane = tid & 63;
    const int r = lane & 15, hh = lane >> 4;
    unsigned* xcat32 = (unsigned*)xcatb;

    // stage weights once: LDS col = g*16 + ul, swizzled
    for (int i = 0; i < 16; i++) {
        int c = i * 128 + tid;
        int col = c >> 5, off = c & 31;
        int g = col >> 4, ul = col & 15;
        sh8 v = *(const sh8*)(whh + ((size_t)(g * 256 + u0 + ul)) * 256 + off * 8);
        *(sh8*)((char*)wlds + col * 512 + ((off * 16) ^ ((col & 7) << 4))) = v;
    }
    __syncthreads();

    const int arow_m = m0 + mt * 16 + r;
    const int u = u0 + r;
    const int mb = m0 + mt * 16 + hh * 4;
    float c_state[4] = {0.f, 0.f, 0.f, 0.f};

    // preload x-gates for first step
    float xv[4][4];
    {
        const int t0 = dir ? 31 : 0;
        #pragma unroll
        for (int g = 0; g < 4; g++)
            #pragma unroll
            for (int reg = 0; reg < 4; reg++)
                xv[g][reg] = xfb[((size_t)t0 * 128 + mb + reg) * 2048 + dir * 1024 + g * 256 + u];
    }

    for (int s = 0; s < 32; s++) {
        const int t = dir ? (31 - s) : s;
        f4 acc[4] = {};
        if (s > 0) {
            grp_wait(grp_flags, 16, s);
            const int tp = dir ? (t + 1) : (t - 1);
            const short* arow = xcatb + ((size_t)tp * 128 + arow_m) * 1024 + dcol + hh * 8;
            u4 afr[8];
            #pragma unroll
            for (int kk = 0; kk < 8; kk++) afr[kk] = cload_u4(arow + kk * 32);
            asm volatile("s_waitcnt vmcnt(0)" ::: "memory");
            __builtin_amdgcn_sched_barrier(0);
            #pragma unroll
            for (int kk = 0; kk < 8; kk++) {
                sh8 af = as_sh8(afr[kk]);
                #pragma unroll
                for (int g = 0; g < 4; g++) {
                    int colr = g * 16 + r;
                    sh8 bf = *(const sh8*)((const char*)wlds + colr * 512 +
                              (((kk * 64 + hh * 16)) ^ ((colr & 7) << 4)));
                    acc[g] = __builtin_amdgcn_mfma_f32_16x16x32_bf16(af, bf, acc[g], 0, 0, 0);
                }
            }
        }
        #pragma unroll
        for (int reg = 0; reg < 4; reg++) {
            int m = mb + reg;
            float gI = acc[0][reg] + xv[0][reg];
            float gF = acc[1][reg] + xv[1][reg];
            float gG = acc[2][reg] + xv[2][reg];
            float gO = acc[3][reg] + xv[3][reg];
            float cn = sigm(gF) * c_state[reg] + sigm(gI) * tanha(gG);
            c_state[reg] = cn;
            float h = sigm(gO) * tanha(cn);
            unsigned hb = (unsigned)(unsigned short)f2bf(h);
            unsigned pb = (unsigned)__shfl_xor((int)hb, 1, 64);
            if (!(r & 1))
                __hip_atomic_store(&xcat32[((size_t)t * 128 + m) * 512 + ((dcol + u) >> 1)],
                                   hb | (pb << 16), __ATOMIC_RELAXED, __HIP_MEMORY_SCOPE_AGENT);
        }
        if (s < 31) {
            grp_signal(my_flag, s + 1);
            // prefetch next step's x-gates under the consumers' poll window
            const int tn = dir ? (t - 1) : (t + 1);
            #pragma unroll
            for (int g = 0; g < 4; g++)
                #pragma unroll
                for (int reg = 0; reg < 4; reg++)
                    xv[g][reg] = xfb[((size_t)tn * 128 + mb + reg) * 2048 + dir * 1024 + g * 256 + u];
        }
    }
}

// ---------------------------------------------------------------------------
// gru_chain: R8-proven form. 128 blocks x 128 thr (2 waves).
// blk: mg=blk>>4 (16-row slice), ug=blk&15 (32-u slice). Group mg = 16 blocks.
// Weights 96KB dynamic LDS. Prefetch after signal.
__global__ __launch_bounds__(128)
void gru_chain(const float* __restrict__ gi,     // [32][128][1536] (incl b_ih)
               const short* __restrict__ gwhh_b, const float* __restrict__ bhh,
               short* __restrict__ gresb,        // [32][128][512]
               int* __restrict__ flags) {        // [8 grp][16 blk][16]
    extern __shared__ short wlds[];              // 96KB: 96 cols x 1024B
    const int blk = blockIdx.x;
    const int mg = blk >> 4, ug = blk & 15;
    const int m0 = mg * 16, u0 = ug * 32;

    int* grp_flags = flags + mg * 16 * 16;
    int* my_flag   = grp_flags + ug * 16;

    const int tid = threadIdx.x, w = tid >> 6, lane = tid & 63;
    const int r = lane & 15, hh = lane >> 4;
    unsigned* gres32 = (unsigned*)gresb;

    // stage weights once: 96 cols (g*32+ul) x 1024B, swizzled
    for (int i = 0; i < 48; i++) {
        int c = i * 128 + tid;
        int col = c >> 6, off = c & 63;
        int g = col >> 5, ul = col & 31;
        sh8 v = *(const sh8*)(gwhh_b + ((size_t)(g * 512 + u0 + ul)) * 512 + off * 8);
        *(sh8*)((char*)wlds + col * 1024 + ((off * 16) ^ ((col & 7) << 4))) = v;
    }
    __syncthreads();

    const int mb = m0 + hh * 4;
    const int u = u0 + w * 16 + r;
    const float bh_r = bhh[u], bh_z = bhh[512 + u], bh_n = bhh[1024 + u];
    float h_state[4] = {0.f, 0.f, 0.f, 0.f};

    float gv[3][4];
    #pragma unroll
    for (int g = 0; g < 3; g++)
        #pragma unroll
        for (int reg = 0; reg < 4; reg++)
            gv[g][reg] = gi[((size_t)(mb + reg)) * 1536 + g * 512 + u];

    for (int t = 0; t < 32; t++) {
        f4 acc[3] = {};
        if (t > 0) {
            grp_wait(grp_flags, 16, t);
            const short* arow = gresb + ((size_t)(t - 1) * 128 + m0 + r) * 512 + hh * 8;
            u4 afr[16];
            #pragma unroll
            for (int kk = 0; kk < 16; kk++) afr[kk] = cload_u4(arow + kk * 32);
            asm volatile("s_waitcnt vmcnt(0)" ::: "memory");
            __builtin_amdgcn_sched_barrier(0);
            #pragma unroll
            for (int kk = 0; kk < 16; kk++) {
                sh8 af = as_sh8(afr[kk]);
                #pragma unroll
                for (int g = 0; g < 3; g++) {
                    int colr = g * 32 + w * 16 + r;
                    sh8 bf = *(const sh8*)((const char*)wlds + colr * 1024 +
                              ((kk * 64 + hh * 16) ^ ((colr & 7) << 4)));
                    acc[g] = __builtin_amdgcn_mfma_f32_16x16x32_bf16(af, bf, acc[g], 0, 0, 0);
                }
            }
        }
        #pragma unroll
        for (int reg = 0; reg < 4; reg++) {
            int m = mb + reg;
            float rr = sigm(gv[0][reg] + acc[0][reg] + bh_r);
            float zz = sigm(gv[1][reg] + acc[1][reg] + bh_z);
            float nn = tanha(gv[2][reg] + rr * (acc[2][reg] + bh_n));
            float h = (1.f - zz) * nn + zz * h_state[reg];
            h_state[reg] = h;
            unsigned hb = (unsigned)(unsigned short)f2bf(h);
            unsigned pb = (unsigned)__shfl_xor((int)hb, 1, 64);
            if (!(r & 1))
                __hip_atomic_store(&gres32[((size_t)t * 128 + m) * 256 + (u >> 1)],
                                   hb | (pb << 16), __ATOMIC_RELAXED, __HIP_MEMORY_SCOPE_AGENT);
        }
        if (t < 31) {
            grp_signal(my_flag, t + 1);
            #pragma unroll
            for (int g = 0; g < 3; g++)
                #pragma unroll
                for (int reg = 0; reg < 4; reg++)
                    gv[g][reg] = gi[((size_t)(t + 1) * 128 + mb + reg) * 1536 + g * 512 + u];
        }
    }
}

// ---------------------------------------------------------------------------
extern "C" void kernel_launch(void* const* d_in, const int* in_sizes, int n_in,
                              void* d_out, int out_size, void* d_ws, size_t ws_size,
                              hipStream_t stream) {
    const float* feature = (const float*)d_in[0];
    const float* attmap  = (const float*)d_in[1];
    const int*   text    = (const int*)d_in[2];
    const float* cemb    = (const float*)d_in[4];
    const float* wihf    = (const float*)d_in[5];
    const float* whhf    = (const float*)d_in[6];
    const float* bihf    = (const float*)d_in[7];
    const float* bhhf    = (const float*)d_in[8];
    const float* wihb    = (const float*)d_in[9];
    const float* whhb    = (const float*)d_in[10];
    const float* bihb    = (const float*)d_in[11];
    const float* bhhb    = (const float*)d_in[12];
    const float* gwih    = (const float*)d_in[13];
    const float* gwhh    = (const float*)d_in[14];
    const float* gbih    = (const float*)d_in[15];
    const float* gbhh    = (const float*)d_in[16];
    const float* genw    = (const float*)d_in[17];
    const float* genb    = (const float*)d_in[18];

    float* out    = (float*)d_out;
    float* outAtt = out + (size_t)4096 * 6625;

    // workspace layout
    float* xfb   = (float*)d_ws;               // [32*128][2048] fwd|bwd gates
    float* gi    = xfb + 8388608;              // [32*128][1536]
    float* biasL = gi + 6291456;               // [2048]
    int*   flags = (int*)(biasL + 2048);       // [4096]: LSTM [0,2048) GRU [2048,4096)
    short* cseqb  = (short*)(flags + 4096);
    short* xcatb  = cseqb + 2097152;
    short* gresb  = xcatb + 4194304;
    short* wih_b  = gresb + 2097152;
    short* whhf_b = wih_b + 1048576;
    short* whhb_b = whhf_b + 262144;
    short* gwih_b = whhb_b + 262144;
    short* gwhh_b = gwih_b + 1572864;
    short* genw_b = gwhh_b + 786432;

    hipFuncSetAttribute((const void*)gru_chain,
                        hipFuncAttributeMaxDynamicSharedMemorySize, 98304);

    zero_ctr<<<dim3(16), dim3(256), 0, stream>>>(flags, 4096);

    CvtPack p;
    p.s[0] = wihf; p.d[0] = wih_b;           p.n4[0] = 524288 / 4;
    p.s[1] = wihb; p.d[1] = wih_b + 524288;  p.n4[1] = 524288 / 4;
    p.s[2] = whhf; p.d[2] = whhf_b;          p.n4[2] = 262144 / 4;
    p.s[3] = whhb; p.d[3] = whhb_b;          p.n4[3] = 262144 / 4;
    p.s[4] = gwih; p.d[4] = gwih_b;          p.n4[4] = 1572864 / 4;
    p.s[5] = gwhh; p.d[5] = gwhh_b;          p.n4[5] = 786432 / 4;
    p.s[6] = genw; p.d[6] = genw_b;          p.n4[6] = 3392000 / 4;
    cvt_bf16<<<dim3(128, 7), dim3(256), 0, stream>>>(p);
    bias_prep<<<dim3(8), dim3(256), 0, stream>>>(bihf, bhhf, bihb, bhhb, biasL);

    att_norm<<<dim3(4096), dim3(64), 0, stream>>>(attmap, outAtt);
    pool_gemm<<<dim3(8, 128), dim3(256), 0, stream>>>(feature, outAtt, cseqb);

    // LSTM input gates (merged fwd+bwd): xfb = cseq @ [wihf;wihb]^T + biasL
    gemm128<0><<<dim3(32, 16), dim3(256), 0, stream>>>(cseqb, wih_b, biasL, nullptr,
                                                       xfb, 4096, 2048, 512);
    emb_fill<<<dim3(4096), dim3(64), 0, stream>>>(text, cemb, xcatb);

    lstm_chain<<<dim3(128), dim3(128), 0, stream>>>(xfb, whhf_b, whhb_b, xcatb, flags);

    gemm128<0><<<dim3(32, 12), dim3(256), 0, stream>>>(xcatb, gwih_b, gbih, nullptr,
                                                       gi, 4096, 1536, 1024);

    gru_chain<<<dim3(128), dim3(128), 98304, stream>>>(gi, gwhh_b, gbhh, gresb, flags + 2048);

    gemm128<1><<<dim3(32, 52), dim3(256), 0, stream>>>(gresb, genw_b, genb, nullptr,
                                                       out, 4096, 6625, 512);
}

// Round 14
// 385.003 us; speedup vs baseline: 1.5117x; 1.0017x over previous
//
#include <hip/hip_runtime.h>
#include <math.h>

typedef __attribute__((ext_vector_type(8))) short sh8;
typedef __attribute__((ext_vector_type(4))) short sh4;
typedef __attribute__((ext_vector_type(4))) float f4;
typedef __attribute__((ext_vector_type(4))) unsigned u4;

__device__ inline short f2bf(float f) {
    union { float f; unsigned u; } v; v.f = f;
    unsigned u = v.u;
    return (short)((u + 0x7fffu + ((u >> 16) & 1u)) >> 16);   // RNE
}
__device__ inline sh8 as_sh8(u4 v) { union { u4 u; sh8 s; } c; c.u = v; return c.s; }

// fast activations: native exp2/rcp, err ~1e-6 (validated R8-R13, absmax 0.0039)
__device__ inline float sigm(float x)  { return __builtin_amdgcn_rcpf(1.f + __builtin_amdgcn_exp2f(-1.44269504f * x)); }
__device__ inline float tanha(float x) { return 1.f - 2.f * __builtin_amdgcn_rcpf(1.f + __builtin_amdgcn_exp2f(2.88539008f * x)); }

__device__ inline sh8 frag8(const float* __restrict__ p) {
    f4 a = *(const f4*)p;
    f4 b = *(const f4*)(p + 4);
    sh8 r;
    r[0]=f2bf(a[0]); r[1]=f2bf(a[1]); r[2]=f2bf(a[2]); r[3]=f2bf(a[3]);
    r[4]=f2bf(b[0]); r[5]=f2bf(b[1]); r[6]=f2bf(b[2]); r[7]=f2bf(b[3]);
    return r;
}

// Coherent 16B load: bypasses L1/L2, reads device coherence point (IF$).
__device__ inline u4 cload_u4(const void* p) {
    u4 r;
    asm volatile("global_load_dwordx4 %0, %1, off sc0 sc1" : "=v"(r) : "v"(p));
    return r;
}

// Group barrier (per-block 64B flag slots, monotonic epochs) — R5/R8 proven.
__device__ inline void grp_signal(int* myflag, int epoch) {
    asm volatile("s_waitcnt vmcnt(0)" ::: "memory");   // h-stores at coherence point
    __builtin_amdgcn_sched_barrier(0);
    __syncthreads();
    if (threadIdx.x == 0)
        __hip_atomic_store(myflag, epoch, __ATOMIC_RELAXED, __HIP_MEMORY_SCOPE_AGENT);
}
__device__ inline void grp_wait(const int* fbase, int nb, int epoch) {
    if (threadIdx.x < 64) {
        int lane = threadIdx.x;
        bool need = lane < nb;
        const int* fp = fbase + lane * 16;
        while (true) {
            int v = need ? __hip_atomic_load(fp, __ATOMIC_RELAXED, __HIP_MEMORY_SCOPE_AGENT)
                         : 0x7fffffff;
            if (__ballot(need && (v < epoch)) == 0ull) break;
            __builtin_amdgcn_s_sleep(1);
        }
    }
    __syncthreads();
}
// drain prefetch loads issued after signal so the NEXT poll is clean
__device__ inline void prefetch_drain() {
    asm volatile("s_waitcnt vmcnt(0)" ::: "memory");
    __builtin_amdgcn_sched_barrier(0);
}

// ---------------------------------------------------------------------------
__global__ void zero_ctr(int* c, int n) {
    int i = blockIdx.x * blockDim.x + threadIdx.x;
    if (i < n) c[i] = 0;
}

// ---------------------------------------------------------------------------
struct CvtPack { const float* s[7]; short* d[7]; int n4[7]; };
__global__ void cvt_bf16(CvtPack p) {
    int job = blockIdx.y;
    const f4* s = (const f4*)p.s[job];
    sh4* d = (sh4*)p.d[job];
    int n4 = p.n4[job];
    for (int i = blockIdx.x * blockDim.x + threadIdx.x; i < n4; i += gridDim.x * blockDim.x) {
        f4 v = s[i];
        sh4 o; o[0]=f2bf(v[0]); o[1]=f2bf(v[1]); o[2]=f2bf(v[2]); o[3]=f2bf(v[3]);
        d[i] = o;
    }
}

__global__ void bias_prep(const float* bihf, const float* bhhf,
                          const float* bihb, const float* bhhb, float* biasL) {
    int n = blockIdx.x * blockDim.x + threadIdx.x;
    biasL[n] = (n < 1024) ? bihf[n] + bhhf[n] : bihb[n - 1024] + bhhb[n - 1024];
}

// ---------------------------------------------------------------------------
__global__ void att_norm(const float* __restrict__ att, float* __restrict__ outA) {
    int row = blockIdx.x;
    int tid = threadIdx.x;
    const float* p = att + (size_t)row * 256;
    f4 v = *(const f4*)(p + tid * 4);
    float sum = v[0] + v[1] + v[2] + v[3];
    #pragma unroll
    for (int off = 32; off; off >>= 1) sum += __shfl_down(sum, off);
    float inv = 1.f / __shfl(sum, 0);
    f4 o; o[0]=v[0]*inv; o[1]=v[1]*inv; o[2]=v[2]*inv; o[3]=v[3]*inv;
    *(f4*)(outA + (size_t)row * 256 + tid * 4) = o;
}

// ---------------------------------------------------------------------------
__global__ __launch_bounds__(256)
void pool_gemm(const float* __restrict__ feature, const float* __restrict__ att,
               short* __restrict__ cseqb) {
    int bz = blockIdx.y;
    const float* A  = feature + (size_t)bz * 512 * 256;
    const float* Wt = att + (size_t)bz * 32 * 256;
    int wave = threadIdx.x >> 6, lane = threadIdx.x & 63, r = lane & 15, hh = lane >> 4;
    int m0 = blockIdx.x * 64 + wave * 16;
    f4 acc[2] = {};
    const float* ar = A  + (size_t)(m0 + r) * 256 + hh * 8;
    const float* w0 = Wt + (size_t)r * 256 + hh * 8;
    const float* w1 = Wt + (size_t)(16 + r) * 256 + hh * 8;
    for (int kk = 0; kk < 256; kk += 32) {
        sh8 af = frag8(ar + kk);
        acc[0] = __builtin_amdgcn_mfma_f32_16x16x32_bf16(af, frag8(w0 + kk), acc[0], 0, 0, 0);
        acc[1] = __builtin_amdgcn_mfma_f32_16x16x32_bf16(af, frag8(w1 + kk), acc[1], 0, 0, 0);
    }
    #pragma unroll
    for (int j = 0; j < 2; j++) {
        int t = j * 16 + r;
        #pragma unroll
        for (int reg = 0; reg < 4; reg++) {
            int c = m0 + hh * 4 + reg;
            cseqb[(size_t)t * 65536 + (size_t)bz * 512 + c] = f2bf(acc[j][reg]);
        }
    }
}

// ---------------------------------------------------------------------------
// gemm128: C[M,N] = A[M,K] @ W[N,K]^T + bias. bf16 operands, fp32 out.
// XCD-aware bijective block swizzle (nwg%8==0 in all uses; identity otherwise).
template<int MODE>
__global__ __launch_bounds__(256)
void gemm128(const short* __restrict__ A, const short* __restrict__ W,
             const float* __restrict__ bias1, const float* __restrict__ bias2,
             float* __restrict__ out, int M, int N, int K) {
    __shared__ short lds[2][2][4096];
    const int tid = threadIdx.x, wave = tid >> 6, lane = tid & 63;
    const int r = lane & 15, hh = lane >> 4;
    const int wm = wave >> 1, wn = wave & 1;

    int bx = blockIdx.x, by = blockIdx.y;
    {
        int gx = gridDim.x;
        int nwg = gx * gridDim.y;
        if ((nwg & 7) == 0) {
            int id = by * gx + bx;
            int cpx = nwg >> 3;
            int swz = (id & 7) * cpx + (id >> 3);
            bx = swz % gx;
            by = swz / gx;
        }
    }
    const int m0 = bx * 128, n0 = by * 128;

    const int c0 = tid, c1 = 256 + tid;
    const int r0 = c0 >> 2, r1 = c1 >> 2;
    const int s0 = ((c0 & 3) ^ ((r0 >> 1) & 3));
    const int s1 = ((c1 & 3) ^ ((r1 >> 1) & 3));
    const short* gA0 = A + (size_t)(m0 + r0) * K + s0 * 8;
    const short* gA1 = A + (size_t)(m0 + r1) * K + s1 * 8;
    int wr0 = n0 + r0; if (wr0 > N - 1) wr0 = N - 1;
    int wr1 = n0 + r1; if (wr1 > N - 1) wr1 = N - 1;
    const short* gW0 = W + (size_t)wr0 * K + s0 * 8;
    const short* gW1 = W + (size_t)wr1 * K + s1 * 8;
    const int lo0 = (wave * 64) * 8, lo1 = (256 + wave * 64) * 8;

    auto stage = [&](int buf, int kt) {
        int ko = kt * 32;
        __builtin_amdgcn_global_load_lds((const __attribute__((address_space(1))) void*)(gA0 + ko),
            (__attribute__((address_space(3))) void*)&lds[buf][0][lo0], 16, 0, 0);
        __builtin_amdgcn_global_load_lds((const __attribute__((address_space(1))) void*)(gA1 + ko),
            (__attribute__((address_space(3))) void*)&lds[buf][0][lo1], 16, 0, 0);
        __builtin_amdgcn_global_load_lds((const __attribute__((address_space(1))) void*)(gW0 + ko),
            (__attribute__((address_space(3))) void*)&lds[buf][1][lo0], 16, 0, 0);
        __builtin_amdgcn_global_load_lds((const __attribute__((address_space(1))) void*)(gW1 + ko),
            (__attribute__((address_space(3))) void*)&lds[buf][1][lo1], 16, 0, 0);
    };

    f4 acc[4][4] = {};
    const int NT = K / 32;
    int cur = 0;

    stage(0, 0);
    __syncthreads();
    for (int kt = 0; kt < NT; ++kt) {
        if (kt + 1 < NT) stage(cur ^ 1, kt + 1);
        const char* As = (const char*)&lds[cur][0][0];
        const char* Ws = (const char*)&lds[cur][1][0];
        sh8 a[4], b[4];
        #pragma unroll
        for (int i = 0; i < 4; i++) {
            int row = wm * 64 + i * 16 + r;
            a[i] = *(const sh8*)(As + row * 64 + ((hh ^ ((row >> 1) & 3)) * 16));
        }
        #pragma unroll
        for (int i = 0; i < 4; i++) {
            int row = wn * 64 + i * 16 + r;
            b[i] = *(const sh8*)(Ws + row * 64 + ((hh ^ ((row >> 1) & 3)) * 16));
        }
        #pragma unroll
        for (int i = 0; i < 4; i++)
            #pragma unroll
            for (int j = 0; j < 4; j++)
                acc[i][j] = __builtin_amdgcn_mfma_f32_16x16x32_bf16(a[i], b[j], acc[i][j], 0, 0, 0);
        __syncthreads();
        cur ^= 1;
    }

    float bsj[4];
    #pragma unroll
    for (int j = 0; j < 4; j++) {
        int n = n0 + wn * 64 + j * 16 + r;
        int nc = n < N ? n : N - 1;
        bsj[j] = (bias1 ? bias1[nc] : 0.f) + (bias2 ? bias2[nc] : 0.f);
    }

    float* fl = (float*)&lds[0][0][0];
    #pragma unroll
    for (int hhalf = 0; hhalf < 2; hhalf++) {
        __syncthreads();
        if (wm == hhalf) {
            #pragma unroll
            for (int i = 0; i < 4; i++)
                #pragma unroll
                for (int j = 0; j < 4; j++) {
                    int col = wn * 64 + j * 16 + r;
                    #pragma unroll
                    for (int reg = 0; reg < 4; reg++)
                        fl[(i * 16 + hh * 4 + reg) * 128 + col] = acc[i][j][reg] + bsj[j];
                }
        }
        __syncthreads();
        #pragma unroll
        for (int it = 0; it < 8; it++) {
            int c = it * 256 + tid;
            int row = c >> 5, cf4 = c & 31;
            int n = n0 + cf4 * 4;
            int mrow = m0 + hhalf * 64 + row;
            size_t orow = (MODE == 0) ? (size_t)mrow
                                      : ((size_t)(mrow & 127) * 32 + (mrow >> 7));
            if (n + 3 < N) {
                *(f4*)&out[orow * N + n] = *(const f4*)&fl[row * 128 + cf4 * 4];
            } else {
                #pragma unroll
                for (int d = 0; d < 4; d++)
                    if (n + d < N) out[orow * N + n + d] = fl[row * 128 + cf4 * 4 + d];
            }
        }
    }
}

// ---------------------------------------------------------------------------
__global__ void emb_fill(const int* __restrict__ text, const float* __restrict__ emb,
                         short* __restrict__ xcatb) {
    int n = blockIdx.x;
    int t = n >> 7, b = n & 127;
    int idx = (t == 0) ? 0 : text[b * 32 + (t - 1)];
    const f4* src = (const f4*)(emb + (size_t)idx * 512);
    sh4* dst = (sh4*)(xcatb + (size_t)n * 1024 + 512);
    for (int j = threadIdx.x; j < 128; j += 64) {
        f4 v = src[j];
        sh4 o; o[0]=f2bf(v[0]); o[1]=f2bf(v[1]); o[2]=f2bf(v[2]); o[3]=f2bf(v[3]);
        dst[j] = o;
    }
}

// ---------------------------------------------------------------------------
// lstm_chain: R5 form + prefetch-drain. 128 blocks x 128 thr (2 waves).
__global__ __launch_bounds__(128)
void lstm_chain(const float* __restrict__ xfb,   // [32][128][2048] gates
                const short* __restrict__ whhf_b, const short* __restrict__ whhb_b,
                short* __restrict__ xcatb,       // [32][128][1024]
                int* __restrict__ flags) {       // [8 grp][16 blk][16]
    __shared__ short wlds[64 * 256];             // 32KB
    const int blk = blockIdx.x;
    const int dir = blk >> 6;
    const int mg  = (blk >> 4) & 3;
    const int ug  = blk & 15;
    const int m0 = mg * 32, u0 = ug * 16;
    const short* whh = dir ? whhb_b : whhf_b;
    const int dcol = dir ? 256 : 0;

    int* grp_flags = flags + (dir * 4 + mg) * 16 * 16;
    int* my_flag   = grp_flags + ug * 16;

    const int tid = threadIdx.x, mt = tid >> 6, lane = tid & 63;
    const int r = lane & 15, hh = lane >> 4;
    unsigned* xcat32 = (unsigned*)xcatb;

    // stage weights once: LDS col = g*16 + ul, swizzled
    for (int i = 0; i < 16; i++) {
        int c = i * 128 + tid;
        int col = c >> 5, off = c & 31;
        int g = col >> 4, ul = col & 15;
        sh8 v = *(const sh8*)(whh + ((size_t)(g * 256 + u0 + ul)) * 256 + off * 8);
        *(sh8*)((char*)wlds + col * 512 + ((off * 16) ^ ((col & 7) << 4))) = v;
    }
    __syncthreads();

    const int arow_m = m0 + mt * 16 + r;
    const int u = u0 + r;
    const int mb = m0 + mt * 16 + hh * 4;
    float c_state[4] = {0.f, 0.f, 0.f, 0.f};

    // preload x-gates for first step
    float xv[4][4];
    {
        const int t0 = dir ? 31 : 0;
        #pragma unroll
        for (int g = 0; g < 4; g++)
            #pragma unroll
            for (int reg = 0; reg < 4; reg++)
                xv[g][reg] = xfb[((size_t)t0 * 128 + mb + reg) * 2048 + dir * 1024 + g * 256 + u];
    }

    for (int s = 0; s < 32; s++) {
        const int t = dir ? (31 - s) : s;
        f4 acc[4] = {};
        if (s > 0) {
            grp_wait(grp_flags, 16, s);          // clean poll (prefetch drained)
            const int tp = dir ? (t + 1) : (t - 1);
            const short* arow = xcatb + ((size_t)tp * 128 + arow_m) * 1024 + dcol + hh * 8;
            u4 afr[8];
            #pragma unroll
            for (int kk = 0; kk < 8; kk++) afr[kk] = cload_u4(arow + kk * 32);
            asm volatile("s_waitcnt vmcnt(0)" ::: "memory");
            __builtin_amdgcn_sched_barrier(0);
            #pragma unroll
            for (int kk = 0; kk < 8; kk++) {
                sh8 af = as_sh8(afr[kk]);
                #pragma unroll
                for (int g = 0; g < 4; g++) {
                    int colr = g * 16 + r;
                    sh8 bf = *(const sh8*)((const char*)wlds + colr * 512 +
                              (((kk * 64 + hh * 16)) ^ ((colr & 7) << 4)));
                    acc[g] = __builtin_amdgcn_mfma_f32_16x16x32_bf16(af, bf, acc[g], 0, 0, 0);
                }
            }
        }
        #pragma unroll
        for (int reg = 0; reg < 4; reg++) {
            int m = mb + reg;
            float gI = acc[0][reg] + xv[0][reg];
            float gF = acc[1][reg] + xv[1][reg];
            float gG = acc[2][reg] + xv[2][reg];
            float gO = acc[3][reg] + xv[3][reg];
            float cn = sigm(gF) * c_state[reg] + sigm(gI) * tanha(gG);
            c_state[reg] = cn;
            float h = sigm(gO) * tanha(cn);
            unsigned hb = (unsigned)(unsigned short)f2bf(h);
            unsigned pb = (unsigned)__shfl_xor((int)hb, 1, 64);
            if (!(r & 1))
                __hip_atomic_store(&xcat32[((size_t)t * 128 + m) * 512 + ((dcol + u) >> 1)],
                                   hb | (pb << 16), __ATOMIC_RELAXED, __HIP_MEMORY_SCOPE_AGENT);
        }
        if (s < 31) {
            grp_signal(my_flag, s + 1);
            // prefetch next step's x-gates, then drain so next poll is clean
            const int tn = dir ? (t - 1) : (t + 1);
            #pragma unroll
            for (int g = 0; g < 4; g++)
                #pragma unroll
                for (int reg = 0; reg < 4; reg++)
                    xv[g][reg] = xfb[((size_t)tn * 128 + mb + reg) * 2048 + dir * 1024 + g * 256 + u];
            prefetch_drain();
        }
    }
}

// ---------------------------------------------------------------------------
// gru_chain: R8 form + prefetch-drain. 128 blocks x 128 thr (2 waves).
__global__ __launch_bounds__(128)
void gru_chain(const float* __restrict__ gi,     // [32][128][1536] (incl b_ih)
               const short* __restrict__ gwhh_b, const float* __restrict__ bhh,
               short* __restrict__ gresb,        // [32][128][512]
               int* __restrict__ flags) {        // [8 grp][16 blk][16]
    extern __shared__ short wlds[];              // 96KB: 96 cols x 1024B
    const int blk = blockIdx.x;
    const int mg = blk >> 4, ug = blk & 15;
    const int m0 = mg * 16, u0 = ug * 32;

    int* grp_flags = flags + mg * 16 * 16;
    int* my_flag   = grp_flags + ug * 16;

    const int tid = threadIdx.x, w = tid >> 6, lane = tid & 63;
    const int r = lane & 15, hh = lane >> 4;
    unsigned* gres32 = (unsigned*)gresb;

    // stage weights once: 96 cols (g*32+ul) x 1024B, swizzled
    for (int i = 0; i < 48; i++) {
        int c = i * 128 + tid;
        int col = c >> 6, off = c & 63;
        int g = col >> 5, ul = col & 31;
        sh8 v = *(const sh8*)(gwhh_b + ((size_t)(g * 512 + u0 + ul)) * 512 + off * 8);
        *(sh8*)((char*)wlds + col * 1024 + ((off * 16) ^ ((col & 7) << 4))) = v;
    }
    __syncthreads();

    const int mb = m0 + hh * 4;
    const int u = u0 + w * 16 + r;
    const float bh_r = bhh[u], bh_z = bhh[512 + u], bh_n = bhh[1024 + u];
    float h_state[4] = {0.f, 0.f, 0.f, 0.f};

    float gv[3][4];
    #pragma unroll
    for (int g = 0; g < 3; g++)
        #pragma unroll
        for (int reg = 0; reg < 4; reg++)
            gv[g][reg] = gi[((size_t)(mb + reg)) * 1536 + g * 512 + u];

    for (int t = 0; t < 32; t++) {
        f4 acc[3] = {};
        if (t > 0) {
            grp_wait(grp_flags, 16, t);          // clean poll (prefetch drained)
            const short* arow = gresb + ((size_t)(t - 1) * 128 + m0 + r) * 512 + hh * 8;
            u4 afr[16];
            #pragma unroll
            for (int kk = 0; kk < 16; kk++) afr[kk] = cload_u4(arow + kk * 32);
            asm volatile("s_waitcnt vmcnt(0)" ::: "memory");
            __builtin_amdgcn_sched_barrier(0);
            #pragma unroll
            for (int kk = 0; kk < 16; kk++) {
                sh8 af = as_sh8(afr[kk]);
                #pragma unroll
                for (int g = 0; g < 3; g++) {
                    int colr = g * 32 + w * 16 + r;
                    sh8 bf = *(const sh8*)((const char*)wlds + colr * 1024 +
                              ((kk * 64 + hh * 16) ^ ((colr & 7) << 4)));
                    acc[g] = __builtin_amdgcn_mfma_f32_16x16x32_bf16(af, bf, acc[g], 0, 0, 0);
                }
            }
        }
        #pragma unroll
        for (int reg = 0; reg < 4; reg++) {
            int m = mb + reg;
            float rr = sigm(gv[0][reg] + acc[0][reg] + bh_r);
            float zz = sigm(gv[1][reg] + acc[1][reg] + bh_z);
            float nn = tanha(gv[2][reg] + rr * (acc[2][reg] + bh_n));
            float h = (1.f - zz) * nn + zz * h_state[reg];
            h_state[reg] = h;
            unsigned hb = (unsigned)(unsigned short)f2bf(h);
            unsigned pb = (unsigned)__shfl_xor((int)hb, 1, 64);
            if (!(r & 1))
                __hip_atomic_store(&gres32[((size_t)t * 128 + m) * 256 + (u >> 1)],
                                   hb | (pb << 16), __ATOMIC_RELAXED, __HIP_MEMORY_SCOPE_AGENT);
        }
        if (t < 31) {
            grp_signal(my_flag, t + 1);
            // prefetch next step's gate-inputs, then drain so next poll is clean
            #pragma unroll
            for (int g = 0; g < 3; g++)
                #pragma unroll
                for (int reg = 0; reg < 4; reg++)
                    gv[g][reg] = gi[((size_t)(t + 1) * 128 + mb + reg) * 1536 + g * 512 + u];
            prefetch_drain();
        }
    }
}

// ---------------------------------------------------------------------------
extern "C" void kernel_launch(void* const* d_in, const int* in_sizes, int n_in,
                              void* d_out, int out_size, void* d_ws, size_t ws_size,
                              hipStream_t stream) {
    const float* feature = (const float*)d_in[0];
    const float* attmap  = (const float*)d_in[1];
    const int*   text    = (const int*)d_in[2];
    const float* cemb    = (const float*)d_in[4];
    const float* wihf    = (const float*)d_in[5];
    const float* whhf    = (const float*)d_in[6];
    const float* bihf    = (const float*)d_in[7];
    const float* bhhf    = (const float*)d_in[8];
    const float* wihb    = (const float*)d_in[9];
    const float* whhb    = (const float*)d_in[10];
    const float* bihb    = (const float*)d_in[11];
    const float* bhhb    = (const float*)d_in[12];
    const float* gwih    = (const float*)d_in[13];
    const float* gwhh    = (const float*)d_in[14];
    const float* gbih    = (const float*)d_in[15];
    const float* gbhh    = (const float*)d_in[16];
    const float* genw    = (const float*)d_in[17];
    const float* genb    = (const float*)d_in[18];

    float* out    = (float*)d_out;
    float* outAtt = out + (size_t)4096 * 6625;

    // workspace layout
    float* xfb   = (float*)d_ws;               // [32*128][2048] fwd|bwd gates
    float* gi    = xfb + 8388608;              // [32*128][1536]
    float* biasL = gi + 6291456;               // [2048]
    int*   flags = (int*)(biasL + 2048);       // [4096]: LSTM [0,2048) GRU [2048,4096)
    short* cseqb  = (short*)(flags + 4096);
    short* xcatb  = cseqb + 2097152;
    short* gresb  = xcatb + 4194304;
    short* wih_b  = gresb + 2097152;
    short* whhf_b = wih_b + 1048576;
    short* whhb_b = whhf_b + 262144;
    short* gwih_b = whhb_b + 262144;
    short* gwhh_b = gwih_b + 1572864;
    short* genw_b = gwhh_b + 786432;

    hipFuncSetAttribute((const void*)gru_chain,
                        hipFuncAttributeMaxDynamicSharedMemorySize, 98304);

    zero_ctr<<<dim3(16), dim3(256), 0, stream>>>(flags, 4096);

    CvtPack p;
    p.s[0] = wihf; p.d[0] = wih_b;           p.n4[0] = 524288 / 4;
    p.s[1] = wihb; p.d[1] = wih_b + 524288;  p.n4[1] = 524288 / 4;
    p.s[2] = whhf; p.d[2] = whhf_b;          p.n4[2] = 262144 / 4;
    p.s[3] = whhb; p.d[3] = whhb_b;          p.n4[3] = 262144 / 4;
    p.s[4] = gwih; p.d[4] = gwih_b;          p.n4[4] = 1572864 / 4;
    p.s[5] = gwhh; p.d[5] = gwhh_b;          p.n4[5] = 786432 / 4;
    p.s[6] = genw; p.d[6] = genw_b;          p.n4[6] = 3392000 / 4;
    cvt_bf16<<<dim3(128, 7), dim3(256), 0, stream>>>(p);
    bias_prep<<<dim3(8), dim3(256), 0, stream>>>(bihf, bhhf, bihb, bhhb, biasL);

    att_norm<<<dim3(4096), dim3(64), 0, stream>>>(attmap, outAtt);
    pool_gemm<<<dim3(8, 128), dim3(256), 0, stream>>>(feature, outAtt, cseqb);

    // LSTM input gates (merged fwd+bwd): xfb = cseq @ [wihf;wihb]^T + biasL
    gemm128<0><<<dim3(32, 16), dim3(256), 0, stream>>>(cseqb, wih_b, biasL, nullptr,
                                                       xfb, 4096, 2048, 512);
    emb_fill<<<dim3(4096), dim3(64), 0, stream>>>(text, cemb, xcatb);

    lstm_chain<<<dim3(128), dim3(128), 0, stream>>>(xfb, whhf_b, whhb_b, xcatb, flags);

    gemm128<0><<<dim3(32, 12), dim3(256), 0, stream>>>(xcatb, gwih_b, gbih, nullptr,
                                                       gi, 4096, 1536, 1024);

    gru_chain<<<dim3(128), dim3(128), 98304, stream>>>(gi, gwhh_b, gbhh, gresb, flags + 2048);

    gemm128<1><<<dim3(32, 52), dim3(256), 0, stream>>>(gresb, genw_b, genb, nullptr,
                                                       out, 4096, 6625, 512);
}

// Round 15
// 375.238 us; speedup vs baseline: 1.5510x; 1.0260x over previous
//
#include <hip/hip_runtime.h>
#include <math.h>

typedef __attribute__((ext_vector_type(8))) short sh8;
typedef __attribute__((ext_vector_type(4))) short sh4;
typedef __attribute__((ext_vector_type(4))) float f4;
typedef __attribute__((ext_vector_type(4))) unsigned u4;

__device__ inline short f2bf(float f) {
    union { float f; unsigned u; } v; v.f = f;
    unsigned u = v.u;
    return (short)((u + 0x7fffu + ((u >> 16) & 1u)) >> 16);   // RNE
}
__device__ inline sh8 as_sh8(u4 v) { union { u4 u; sh8 s; } c; c.u = v; return c.s; }

// fast activations: native exp2/rcp, err ~1e-6 (validated R8-R14, absmax 0.0039)
__device__ inline float sigm(float x)  { return __builtin_amdgcn_rcpf(1.f + __builtin_amdgcn_exp2f(-1.44269504f * x)); }
__device__ inline float tanha(float x) { return 1.f - 2.f * __builtin_amdgcn_rcpf(1.f + __builtin_amdgcn_exp2f(2.88539008f * x)); }

__device__ inline sh8 frag8(const float* __restrict__ p) {
    f4 a = *(const f4*)p;
    f4 b = *(const f4*)(p + 4);
    sh8 r;
    r[0]=f2bf(a[0]); r[1]=f2bf(a[1]); r[2]=f2bf(a[2]); r[3]=f2bf(a[3]);
    r[4]=f2bf(b[0]); r[5]=f2bf(b[1]); r[6]=f2bf(b[2]); r[7]=f2bf(b[3]);
    return r;
}

// Coherent 16B load: bypasses L1/L2, reads device coherence point (IF$).
__device__ inline u4 cload_u4(const void* p) {
    u4 r;
    asm volatile("global_load_dwordx4 %0, %1, off sc0 sc1" : "=v"(r) : "v"(p));
    return r;
}

// Group barrier (per-block 64B flag slots, monotonic epochs) — R5/R8 proven.
__device__ inline void grp_signal(int* myflag, int epoch) {
    asm volatile("s_waitcnt vmcnt(0)" ::: "memory");
    __builtin_amdgcn_sched_barrier(0);
    __syncthreads();
    if (threadIdx.x == 0)
        __hip_atomic_store(myflag, epoch, __ATOMIC_RELAXED, __HIP_MEMORY_SCOPE_AGENT);
}
__device__ inline void grp_wait(const int* fbase, int nb, int epoch) {
    if (threadIdx.x < 64) {
        int lane = threadIdx.x;
        bool need = lane < nb;
        const int* fp = fbase + lane * 16;
        while (true) {
            int v = need ? __hip_atomic_load(fp, __ATOMIC_RELAXED, __HIP_MEMORY_SCOPE_AGENT)
                         : 0x7fffffff;
            if (__ballot(need && (v < epoch)) == 0ull) break;
            __builtin_amdgcn_s_sleep(1);
        }
    }
    __syncthreads();
}
__device__ inline void prefetch_drain() {
    asm volatile("s_waitcnt vmcnt(0)" ::: "memory");
    __builtin_amdgcn_sched_barrier(0);
}

// ---------------------------------------------------------------------------
// prep: zero flags (4096 ints) + merged LSTM bias (2048 floats), one launch
__global__ void prep(int* flags, const float* bihf, const float* bhhf,
                     const float* bihb, const float* bhhb, float* biasL) {
    int i = blockIdx.x * blockDim.x + threadIdx.x;     // 0..4095
    flags[i] = 0;
    if (i < 2048)
        biasL[i] = (i < 1024) ? bihf[i] + bhhf[i] : bihb[i - 1024] + bhhb[i - 1024];
}

// ---------------------------------------------------------------------------
struct CvtPack { const float* s[7]; short* d[7]; int n4[7]; };
__global__ void cvt_bf16(CvtPack p) {
    int job = blockIdx.y;
    const f4* s = (const f4*)p.s[job];
    sh4* d = (sh4*)p.d[job];
    int n4 = p.n4[job];
    for (int i = blockIdx.x * blockDim.x + threadIdx.x; i < n4; i += gridDim.x * blockDim.x) {
        f4 v = s[i];
        sh4 o; o[0]=f2bf(v[0]); o[1]=f2bf(v[1]); o[2]=f2bf(v[2]); o[3]=f2bf(v[3]);
        d[i] = o;
    }
}

// ---------------------------------------------------------------------------
__global__ void att_norm(const float* __restrict__ att, float* __restrict__ outA) {
    int row = blockIdx.x;
    int tid = threadIdx.x;
    const float* p = att + (size_t)row * 256;
    f4 v = *(const f4*)(p + tid * 4);
    float sum = v[0] + v[1] + v[2] + v[3];
    #pragma unroll
    for (int off = 32; off; off >>= 1) sum += __shfl_down(sum, off);
    float inv = 1.f / __shfl(sum, 0);
    f4 o; o[0]=v[0]*inv; o[1]=v[1]*inv; o[2]=v[2]*inv; o[3]=v[3]*inv;
    *(f4*)(outA + (size_t)row * 256 + tid * 4) = o;
}

// ---------------------------------------------------------------------------
__global__ __launch_bounds__(256)
void pool_gemm(const float* __restrict__ feature, const float* __restrict__ att,
               short* __restrict__ cseqb) {
    int bz = blockIdx.y;
    const float* A  = feature + (size_t)bz * 512 * 256;
    const float* Wt = att + (size_t)bz * 32 * 256;
    int wave = threadIdx.x >> 6, lane = threadIdx.x & 63, r = lane & 15, hh = lane >> 4;
    int m0 = blockIdx.x * 64 + wave * 16;
    f4 acc[2] = {};
    const float* ar = A  + (size_t)(m0 + r) * 256 + hh * 8;
    const float* w0 = Wt + (size_t)r * 256 + hh * 8;
    const float* w1 = Wt + (size_t)(16 + r) * 256 + hh * 8;
    for (int kk = 0; kk < 256; kk += 32) {
        sh8 af = frag8(ar + kk);
        acc[0] = __builtin_amdgcn_mfma_f32_16x16x32_bf16(af, frag8(w0 + kk), acc[0], 0, 0, 0);
        acc[1] = __builtin_amdgcn_mfma_f32_16x16x32_bf16(af, frag8(w1 + kk), acc[1], 0, 0, 0);
    }
    #pragma unroll
    for (int j = 0; j < 2; j++) {
        int t = j * 16 + r;
        #pragma unroll
        for (int reg = 0; reg < 4; reg++) {
            int c = m0 + hh * 4 + reg;
            cseqb[(size_t)t * 65536 + (size_t)bz * 512 + c] = f2bf(acc[j][reg]);
        }
    }
}

// ---------------------------------------------------------------------------
// gemm128: C[M,N] = A[M,K] @ W[N,K]^T + bias. bf16 operands, fp32 out. MODE 0.
__global__ __launch_bounds__(256)
void gemm128(const short* __restrict__ A, const short* __restrict__ W,
             const float* __restrict__ bias1, const float* __restrict__ bias2,
             float* __restrict__ out, int M, int N, int K) {
    __shared__ short lds[2][2][4096];
    const int tid = threadIdx.x, wave = tid >> 6, lane = tid & 63;
    const int r = lane & 15, hh = lane >> 4;
    const int wm = wave >> 1, wn = wave & 1;

    int bx = blockIdx.x, by = blockIdx.y;
    {
        int gx = gridDim.x;
        int nwg = gx * gridDim.y;
        if ((nwg & 7) == 0) {
            int id = by * gx + bx;
            int cpx = nwg >> 3;
            int swz = (id & 7) * cpx + (id >> 3);
            bx = swz % gx;
            by = swz / gx;
        }
    }
    const int m0 = bx * 128, n0 = by * 128;

    const int c0 = tid, c1 = 256 + tid;
    const int r0 = c0 >> 2, r1 = c1 >> 2;
    const int s0 = ((c0 & 3) ^ ((r0 >> 1) & 3));
    const int s1 = ((c1 & 3) ^ ((r1 >> 1) & 3));
    const short* gA0 = A + (size_t)(m0 + r0) * K + s0 * 8;
    const short* gA1 = A + (size_t)(m0 + r1) * K + s1 * 8;
    int wr0 = n0 + r0; if (wr0 > N - 1) wr0 = N - 1;
    int wr1 = n0 + r1; if (wr1 > N - 1) wr1 = N - 1;
    const short* gW0 = W + (size_t)wr0 * K + s0 * 8;
    const short* gW1 = W + (size_t)wr1 * K + s1 * 8;
    const int lo0 = (wave * 64) * 8, lo1 = (256 + wave * 64) * 8;

    auto stage = [&](int buf, int kt) {
        int ko = kt * 32;
        __builtin_amdgcn_global_load_lds((const __attribute__((address_space(1))) void*)(gA0 + ko),
            (__attribute__((address_space(3))) void*)&lds[buf][0][lo0], 16, 0, 0);
        __builtin_amdgcn_global_load_lds((const __attribute__((address_space(1))) void*)(gA1 + ko),
            (__attribute__((address_space(3))) void*)&lds[buf][0][lo1], 16, 0, 0);
        __builtin_amdgcn_global_load_lds((const __attribute__((address_space(1))) void*)(gW0 + ko),
            (__attribute__((address_space(3))) void*)&lds[buf][1][lo0], 16, 0, 0);
        __builtin_amdgcn_global_load_lds((const __attribute__((address_space(1))) void*)(gW1 + ko),
            (__attribute__((address_space(3))) void*)&lds[buf][1][lo1], 16, 0, 0);
    };

    f4 acc[4][4] = {};
    const int NT = K / 32;
    int cur = 0;

    stage(0, 0);
    __syncthreads();
    for (int kt = 0; kt < NT; ++kt) {
        if (kt + 1 < NT) stage(cur ^ 1, kt + 1);
        const char* As = (const char*)&lds[cur][0][0];
        const char* Ws = (const char*)&lds[cur][1][0];
        sh8 a[4], b[4];
        #pragma unroll
        for (int i = 0; i < 4; i++) {
            int row = wm * 64 + i * 16 + r;
            a[i] = *(const sh8*)(As + row * 64 + ((hh ^ ((row >> 1) & 3)) * 16));
        }
        #pragma unroll
        for (int i = 0; i < 4; i++) {
            int row = wn * 64 + i * 16 + r;
            b[i] = *(const sh8*)(Ws + row * 64 + ((hh ^ ((row >> 1) & 3)) * 16));
        }
        #pragma unroll
        for (int i = 0; i < 4; i++)
            #pragma unroll
            for (int j = 0; j < 4; j++)
                acc[i][j] = __builtin_amdgcn_mfma_f32_16x16x32_bf16(a[i], b[j], acc[i][j], 0, 0, 0);
        __syncthreads();
        cur ^= 1;
    }

    float bsj[4];
    #pragma unroll
    for (int j = 0; j < 4; j++) {
        int n = n0 + wn * 64 + j * 16 + r;
        int nc = n < N ? n : N - 1;
        bsj[j] = (bias1 ? bias1[nc] : 0.f) + (bias2 ? bias2[nc] : 0.f);
    }

    float* fl = (float*)&lds[0][0][0];
    #pragma unroll
    for (int hhalf = 0; hhalf < 2; hhalf++) {
        __syncthreads();
        if (wm == hhalf) {
            #pragma unroll
            for (int i = 0; i < 4; i++)
                #pragma unroll
                for (int j = 0; j < 4; j++) {
                    int col = wn * 64 + j * 16 + r;
                    #pragma unroll
                    for (int reg = 0; reg < 4; reg++)
                        fl[(i * 16 + hh * 4 + reg) * 128 + col] = acc[i][j][reg] + bsj[j];
                }
        }
        __syncthreads();
        #pragma unroll
        for (int it = 0; it < 8; it++) {
            int c = it * 256 + tid;
            int row = c >> 5, cf4 = c & 31;
            int n = n0 + cf4 * 4;
            int mrow = m0 + hhalf * 64 + row;
            if (n + 3 < N) {
                *(f4*)&out[(size_t)mrow * N + n] = *(const f4*)&fl[row * 128 + cf4 * 4];
            } else {
                #pragma unroll
                for (int d = 0; d < 4; d++)
                    if (n + d < N) out[(size_t)mrow * N + n + d] = fl[row * 128 + cf4 * 4 + d];
            }
        }
    }
}

// ---------------------------------------------------------------------------
// gemm256: 256x128 tile, 512 threads (8 waves: wm=wave>>1 in 0..3, wn=wave&1).
// For the logits GEMM (MODE-1 row remap baked in). 48KB LDS double-buffered;
// LDS-staged epilogue in 4 quarters.
__global__ __launch_bounds__(512)
void gemm256(const short* __restrict__ A, const short* __restrict__ W,
             const float* __restrict__ bias1,
             float* __restrict__ out, int M, int N, int K) {
    __shared__ short lds[2][12288];     // per buf: A 256x32 @ [0,8192), W 128x32 @ [8192,12288)
    const int tid = threadIdx.x, wave = tid >> 6, lane = tid & 63;
    const int r = lane & 15, hh = lane >> 4;
    const int wm = wave >> 1, wn = wave & 1;

    int bx = blockIdx.x, by = blockIdx.y;
    {
        int gx = gridDim.x;
        int nwg = gx * gridDim.y;
        if ((nwg & 7) == 0) {
            int id = by * gx + bx;
            int cpx = nwg >> 3;
            int swz = (id & 7) * cpx + (id >> 3);
            bx = swz % gx;
            by = swz / gx;
        }
    }
    const int m0 = bx * 256, n0 = by * 128;

    // staging: A chunks tid and 512+tid (1024 total); W chunk tid (512 total)
    const int cA0 = tid, cA1 = 512 + tid, cW = tid;
    const int rA0 = cA0 >> 2, rA1 = cA1 >> 2, rW = cW >> 2;
    const int sA0 = (cA0 & 3) ^ ((rA0 >> 1) & 3);
    const int sA1 = (cA1 & 3) ^ ((rA1 >> 1) & 3);
    const int sW  = (cW & 3) ^ ((rW >> 1) & 3);
    const short* gA0 = A + (size_t)(m0 + rA0) * K + sA0 * 8;
    const short* gA1 = A + (size_t)(m0 + rA1) * K + sA1 * 8;
    int wrW = n0 + rW; if (wrW > N - 1) wrW = N - 1;
    const short* gW0 = W + (size_t)wrW * K + sW * 8;
    const int loA0 = (wave * 64) * 8, loA1 = (512 + wave * 64) * 8;
    const int loW  = 8192 + (wave * 64) * 8;

    auto stage = [&](int buf, int kt) {
        int ko = kt * 32;
        __builtin_amdgcn_global_load_lds((const __attribute__((address_space(1))) void*)(gA0 + ko),
            (__attribute__((address_space(3))) void*)&lds[buf][loA0], 16, 0, 0);
        __builtin_amdgcn_global_load_lds((const __attribute__((address_space(1))) void*)(gA1 + ko),
            (__attribute__((address_space(3))) void*)&lds[buf][loA1], 16, 0, 0);
        __builtin_amdgcn_global_load_lds((const __attribute__((address_space(1))) void*)(gW0 + ko),
            (__attribute__((address_space(3))) void*)&lds[buf][loW], 16, 0, 0);
    };

    f4 acc[4][4] = {};
    const int NT = K / 32;
    int cur = 0;

    stage(0, 0);
    __syncthreads();
    for (int kt = 0; kt < NT; ++kt) {
        if (kt + 1 < NT) stage(cur ^ 1, kt + 1);
        const char* As = (const char*)&lds[cur][0];
        const char* Ws = (const char*)&lds[cur][8192];
        sh8 a[4], b[4];
        #pragma unroll
        for (int i = 0; i < 4; i++) {
            int row = wm * 64 + i * 16 + r;          // 0..255
            a[i] = *(const sh8*)(As + row * 64 + ((hh ^ ((row >> 1) & 3)) * 16));
        }
        #pragma unroll
        for (int i = 0; i < 4; i++) {
            int row = wn * 64 + i * 16 + r;          // 0..127
            b[i] = *(const sh8*)(Ws + row * 64 + ((hh ^ ((row >> 1) & 3)) * 16));
        }
        #pragma unroll
        for (int i = 0; i < 4; i++)
            #pragma unroll
            for (int j = 0; j < 4; j++)
                acc[i][j] = __builtin_amdgcn_mfma_f32_16x16x32_bf16(a[i], b[j], acc[i][j], 0, 0, 0);
        __syncthreads();
        cur ^= 1;
    }

    float bsj[4];
    #pragma unroll
    for (int j = 0; j < 4; j++) {
        int n = n0 + wn * 64 + j * 16 + r;
        int nc = n < N ? n : N - 1;
        bsj[j] = bias1 ? bias1[nc] : 0.f;
    }

    // epilogue: 4 quarters of 64 rows x 128 cols fp32 (32KB) staged in LDS
    float* fl = (float*)&lds[0][0];
    #pragma unroll
    for (int q = 0; q < 4; q++) {
        __syncthreads();
        if (wm == q) {
            #pragma unroll
            for (int i = 0; i < 4; i++)
                #pragma unroll
                for (int j = 0; j < 4; j++) {
                    int col = wn * 64 + j * 16 + r;
                    #pragma unroll
                    for (int reg = 0; reg < 4; reg++)
                        fl[(i * 16 + hh * 4 + reg) * 128 + col] = acc[i][j][reg] + bsj[j];
                }
        }
        __syncthreads();
        #pragma unroll
        for (int it = 0; it < 4; it++) {
            int c = it * 512 + tid;                  // 2048 f4-chunks
            int row = c >> 5, cf4 = c & 31;
            int n = n0 + cf4 * 4;
            int mrow = m0 + q * 64 + row;
            size_t orow = (size_t)(mrow & 127) * 32 + (mrow >> 7);   // logits remap
            if (n + 3 < N) {
                *(f4*)&out[orow * N + n] = *(const f4*)&fl[row * 128 + cf4 * 4];
            } else {
                #pragma unroll
                for (int d = 0; d < 4; d++)
                    if (n + d < N) out[orow * N + n + d] = fl[row * 128 + cf4 * 4 + d];
            }
        }
    }
}

// ---------------------------------------------------------------------------
__global__ void emb_fill(const int* __restrict__ text, const float* __restrict__ emb,
                         short* __restrict__ xcatb) {
    int n = blockIdx.x;
    int t = n >> 7, b = n & 127;
    int idx = (t == 0) ? 0 : text[b * 32 + (t - 1)];
    const f4* src = (const f4*)(emb + (size_t)idx * 512);
    sh4* dst = (sh4*)(xcatb + (size_t)n * 1024 + 512);
    for (int j = threadIdx.x; j < 128; j += 64) {
        f4 v = src[j];
        sh4 o; o[0]=f2bf(v[0]); o[1]=f2bf(v[1]); o[2]=f2bf(v[2]); o[3]=f2bf(v[3]);
        dst[j] = o;
    }
}

// ---------------------------------------------------------------------------
// lstm_chain: R5 form + prefetch-drain. 128 blocks x 128 thr (2 waves).
__global__ __launch_bounds__(128)
void lstm_chain(const float* __restrict__ xfb,
                const short* __restrict__ whhf_b, const short* __restrict__ whhb_b,
                short* __restrict__ xcatb,
                int* __restrict__ flags) {
    __shared__ short wlds[64 * 256];
    const int blk = blockIdx.x;
    const int dir = blk >> 6;
    const int mg  = (blk >> 4) & 3;
    const int ug  = blk & 15;
    const int m0 = mg * 32, u0 = ug * 16;
    const short* whh = dir ? whhb_b : whhf_b;
    const int dcol = dir ? 256 : 0;

    int* grp_flags = flags + (dir * 4 + mg) * 16 * 16;
    int* my_flag   = grp_flags + ug * 16;

    const int tid = threadIdx.x, mt = tid >> 6, lane = tid & 63;
    const int r = lane & 15, hh = lane >> 4;
    unsigned* xcat32 = (unsigned*)xcatb;

    for (int i = 0; i < 16; i++) {
        int c = i * 128 + tid;
        int col = c >> 5, off = c & 31;
        int g = col >> 4, ul = col & 15;
        sh8 v = *(const sh8*)(whh + ((size_t)(g * 256 + u0 + ul)) * 256 + off * 8);
        *(sh8*)((char*)wlds + col * 512 + ((off * 16) ^ ((col & 7) << 4))) = v;
    }
    __syncthreads();

    const int arow_m = m0 + mt * 16 + r;
    const int u = u0 + r;
    const int mb = m0 + mt * 16 + hh * 4;
    float c_state[4] = {0.f, 0.f, 0.f, 0.f};

    float xv[4][4];
    {
        const int t0 = dir ? 31 : 0;
        #pragma unroll
        for (int g = 0; g < 4; g++)
            #pragma unroll
            for (int reg = 0; reg < 4; reg++)
                xv[g][reg] = xfb[((size_t)t0 * 128 + mb + reg) * 2048 + dir * 1024 + g * 256 + u];
    }

    for (int s = 0; s < 32; s++) {
        const int t = dir ? (31 - s) : s;
        f4 acc[4] = {};
        if (s > 0) {
            grp_wait(grp_flags, 16, s);
            const int tp = dir ? (t + 1) : (t - 1);
            const short* arow = xcatb + ((size_t)tp * 128 + arow_m) * 1024 + dcol + hh * 8;
            u4 afr[8];
            #pragma unroll
            for (int kk = 0; kk < 8; kk++) afr[kk] = cload_u4(arow + kk * 32);
            asm volatile("s_waitcnt vmcnt(0)" ::: "memory");
            __builtin_amdgcn_sched_barrier(0);
            #pragma unroll
            for (int kk = 0; kk < 8; kk++) {
                sh8 af = as_sh8(afr[kk]);
                #pragma unroll
                for (int g = 0; g < 4; g++) {
                    int colr = g * 16 + r;
                    sh8 bf = *(const sh8*)((const char*)wlds + colr * 512 +
                              (((kk * 64 + hh * 16)) ^ ((colr & 7) << 4)));
                    acc[g] = __builtin_amdgcn_mfma_f32_16x16x32_bf16(af, bf, acc[g], 0, 0, 0);
                }
            }
        }
        #pragma unroll
        for (int reg = 0; reg < 4; reg++) {
            int m = mb + reg;
            float gI = acc[0][reg] + xv[0][reg];
            float gF = acc[1][reg] + xv[1][reg];
            float gG = acc[2][reg] + xv[2][reg];
            float gO = acc[3][reg] + xv[3][reg];
            float cn = sigm(gF) * c_state[reg] + sigm(gI) * tanha(gG);
            c_state[reg] = cn;
            float h = sigm(gO) * tanha(cn);
            unsigned hb = (unsigned)(unsigned short)f2bf(h);
            unsigned pb = (unsigned)__shfl_xor((int)hb, 1, 64);
            if (!(r & 1))
                __hip_atomic_store(&xcat32[((size_t)t * 128 + m) * 512 + ((dcol + u) >> 1)],
                                   hb | (pb << 16), __ATOMIC_RELAXED, __HIP_MEMORY_SCOPE_AGENT);
        }
        if (s < 31) {
            grp_signal(my_flag, s + 1);
            const int tn = dir ? (t - 1) : (t + 1);
            #pragma unroll
            for (int g = 0; g < 4; g++)
                #pragma unroll
                for (int reg = 0; reg < 4; reg++)
                    xv[g][reg] = xfb[((size_t)tn * 128 + mb + reg) * 2048 + dir * 1024 + g * 256 + u];
            prefetch_drain();
        }
    }
}

// ---------------------------------------------------------------------------
// gru_chain: R8 form + prefetch-drain. 128 blocks x 128 thr (2 waves).
__global__ __launch_bounds__(128)
void gru_chain(const float* __restrict__ gi,
               const short* __restrict__ gwhh_b, const float* __restrict__ bhh,
               short* __restrict__ gresb,
               int* __restrict__ flags) {
    extern __shared__ short wlds[];
    const int blk = blockIdx.x;
    const int mg = blk >> 4, ug = blk & 15;
    const int m0 = mg * 16, u0 = ug * 32;

    int* grp_flags = flags + mg * 16 * 16;
    int* my_flag   = grp_flags + ug * 16;

    const int tid = threadIdx.x, w = tid >> 6, lane = tid & 63;
    const int r = lane & 15, hh = lane >> 4;
    unsigned* gres32 = (unsigned*)gresb;

    for (int i = 0; i < 48; i++) {
        int c = i * 128 + tid;
        int col = c >> 6, off = c & 63;
        int g = col >> 5, ul = col & 31;
        sh8 v = *(const sh8*)(gwhh_b + ((size_t)(g * 512 + u0 + ul)) * 512 + off * 8);
        *(sh8*)((char*)wlds + col * 1024 + ((off * 16) ^ ((col & 7) << 4))) = v;
    }
    __syncthreads();

    const int mb = m0 + hh * 4;
    const int u = u0 + w * 16 + r;
    const float bh_r = bhh[u], bh_z = bhh[512 + u], bh_n = bhh[1024 + u];
    float h_state[4] = {0.f, 0.f, 0.f, 0.f};

    float gv[3][4];
    #pragma unroll
    for (int g = 0; g < 3; g++)
        #pragma unroll
        for (int reg = 0; reg < 4; reg++)
            gv[g][reg] = gi[((size_t)(mb + reg)) * 1536 + g * 512 + u];

    for (int t = 0; t < 32; t++) {
        f4 acc[3] = {};
        if (t > 0) {
            grp_wait(grp_flags, 16, t);
            const short* arow = gresb + ((size_t)(t - 1) * 128 + m0 + r) * 512 + hh * 8;
            u4 afr[16];
            #pragma unroll
            for (int kk = 0; kk < 16; kk++) afr[kk] = cload_u4(arow + kk * 32);
            asm volatile("s_waitcnt vmcnt(0)" ::: "memory");
            __builtin_amdgcn_sched_barrier(0);
            #pragma unroll
            for (int kk = 0; kk < 16; kk++) {
                sh8 af = as_sh8(afr[kk]);
                #pragma unroll
                for (int g = 0; g < 3; g++) {
                    int colr = g * 32 + w * 16 + r;
                    sh8 bf = *(const sh8*)((const char*)wlds + colr * 1024 +
                              ((kk * 64 + hh * 16) ^ ((colr & 7) << 4)));
                    acc[g] = __builtin_amdgcn_mfma_f32_16x16x32_bf16(af, bf, acc[g], 0, 0, 0);
                }
            }
        }
        #pragma unroll
        for (int reg = 0; reg < 4; reg++) {
            int m = mb + reg;
            float rr = sigm(gv[0][reg] + acc[0][reg] + bh_r);
            float zz = sigm(gv[1][reg] + acc[1][reg] + bh_z);
            float nn = tanha(gv[2][reg] + rr * (acc[2][reg] + bh_n));
            float h = (1.f - zz) * nn + zz * h_state[reg];
            h_state[reg] = h;
            unsigned hb = (unsigned)(unsigned short)f2bf(h);
            unsigned pb = (unsigned)__shfl_xor((int)hb, 1, 64);
            if (!(r & 1))
                __hip_atomic_store(&gres32[((size_t)t * 128 + m) * 256 + (u >> 1)],
                                   hb | (pb << 16), __ATOMIC_RELAXED, __HIP_MEMORY_SCOPE_AGENT);
        }
        if (t < 31) {
            grp_signal(my_flag, t + 1);
            #pragma unroll
            for (int g = 0; g < 3; g++)
                #pragma unroll
                for (int reg = 0; reg < 4; reg++)
                    gv[g][reg] = gi[((size_t)(t + 1) * 128 + mb + reg) * 1536 + g * 512 + u];
            prefetch_drain();
        }
    }
}

// ---------------------------------------------------------------------------
extern "C" void kernel_launch(void* const* d_in, const int* in_sizes, int n_in,
                              void* d_out, int out_size, void* d_ws, size_t ws_size,
                              hipStream_t stream) {
    const float* feature = (const float*)d_in[0];
    const float* attmap  = (const float*)d_in[1];
    const int*   text    = (const int*)d_in[2];
    const float* cemb    = (const float*)d_in[4];
    const float* wihf    = (const float*)d_in[5];
    const float* whhf    = (const float*)d_in[6];
    const float* bihf    = (const float*)d_in[7];
    const float* bhhf    = (const float*)d_in[8];
    const float* wihb    = (const float*)d_in[9];
    const float* whhb    = (const float*)d_in[10];
    const float* bihb    = (const float*)d_in[11];
    const float* bhhb    = (const float*)d_in[12];
    const float* gwih    = (const float*)d_in[13];
    const float* gwhh    = (const float*)d_in[14];
    const float* gbih    = (const float*)d_in[15];
    const float* gbhh    = (const float*)d_in[16];
    const float* genw    = (const float*)d_in[17];
    const float* genb    = (const float*)d_in[18];

    float* out    = (float*)d_out;
    float* outAtt = out + (size_t)4096 * 6625;

    // workspace layout
    float* xfb   = (float*)d_ws;               // [32*128][2048] fwd|bwd gates
    float* gi    = xfb + 8388608;              // [32*128][1536]
    float* biasL = gi + 6291456;               // [2048]
    int*   flags = (int*)(biasL + 2048);       // [4096]: LSTM [0,2048) GRU [2048,4096)
    short* cseqb  = (short*)(flags + 4096);
    short* xcatb  = cseqb + 2097152;
    short* gresb  = xcatb + 4194304;
    short* wih_b  = gresb + 2097152;
    short* whhf_b = wih_b + 1048576;
    short* whhb_b = whhf_b + 262144;
    short* gwih_b = whhb_b + 262144;
    short* gwhh_b = gwih_b + 1572864;
    short* genw_b = gwhh_b + 786432;

    hipFuncSetAttribute((const void*)gru_chain,
                        hipFuncAttributeMaxDynamicSharedMemorySize, 98304);

    prep<<<dim3(16), dim3(256), 0, stream>>>(flags, bihf, bhhf, bihb, bhhb, biasL);

    CvtPack p;
    p.s[0] = wihf; p.d[0] = wih_b;           p.n4[0] = 524288 / 4;
    p.s[1] = wihb; p.d[1] = wih_b + 524288;  p.n4[1] = 524288 / 4;
    p.s[2] = whhf; p.d[2] = whhf_b;          p.n4[2] = 262144 / 4;
    p.s[3] = whhb; p.d[3] = whhb_b;          p.n4[3] = 262144 / 4;
    p.s[4] = gwih; p.d[4] = gwih_b;          p.n4[4] = 1572864 / 4;
    p.s[5] = gwhh; p.d[5] = gwhh_b;          p.n4[5] = 786432 / 4;
    p.s[6] = genw; p.d[6] = genw_b;          p.n4[6] = 3392000 / 4;
    cvt_bf16<<<dim3(128, 7), dim3(256), 0, stream>>>(p);

    att_norm<<<dim3(4096), dim3(64), 0, stream>>>(attmap, outAtt);
    pool_gemm<<<dim3(8, 128), dim3(256), 0, stream>>>(feature, outAtt, cseqb);

    // LSTM input gates (merged fwd+bwd): xfb = cseq @ [wihf;wihb]^T + biasL
    gemm128<<<dim3(32, 16), dim3(256), 0, stream>>>(cseqb, wih_b, biasL, nullptr,
                                                    xfb, 4096, 2048, 512);
    emb_fill<<<dim3(4096), dim3(64), 0, stream>>>(text, cemb, xcatb);

    lstm_chain<<<dim3(128), dim3(128), 0, stream>>>(xfb, whhf_b, whhb_b, xcatb, flags);

    gemm128<<<dim3(32, 12), dim3(256), 0, stream>>>(xcatb, gwih_b, gbih, nullptr,
                                                    gi, 4096, 1536, 1024);

    gru_chain<<<dim3(128), dim3(128), 98304, stream>>>(gi, gwhh_b, gbhh, gresb, flags + 2048);

    // logits: 256x128-tile GEMM with b*T+t remap
    gemm256<<<dim3(16, 52), dim3(512), 0, stream>>>(gresb, genw_b, genb,
                                                    out, 4096, 6625, 512);
}